// Round 2
// baseline (2331.325 us; speedup 1.0000x reference)
//
#include <hip/hip_runtime.h>
#include <math.h>

#define PI2 6.283185307179586f

__device__ __forceinline__ float gelu_f(float x) {
    return 0.5f * x * (1.0f + erff(x * 0.7071067811865476f));
}

// ---------------- bases: planes [b][k][x] k<32: cos, 32..63: sin ----------------
__global__ void k_bases(const float* __restrict__ nodes, const float* __restrict__ modes,
                        const float* __restrict__ latent, float* __restrict__ out, int N) {
    int b = blockIdx.y;
    int x = blockIdx.x * 256 + threadIdx.x;
    float s0 = 0.5f + 1.5f / (1.0f + expf(-latent[0]));
    float s1 = 0.5f + 1.5f / (1.0f + expf(-latent[1]));
    float n0 = nodes[((size_t)b * N + x) * 2 + 0];
    float n1 = nodes[((size_t)b * N + x) * 2 + 1];
    float* ob = out + (size_t)b * 64 * N;
    for (int k = 0; k < 32; ++k) {
        float m0 = modes[k * 2 + 0] * s0;
        float m1 = modes[k * 2 + 1] * s1;
        float t = PI2 * (n0 * m0 + n1 * m1);
        float s, c;
        sincosf(t, &s, &c);
        ob[(size_t)k * N + x] = c;
        ob[(size_t)(32 + k) * N + x] = s;
    }
}

// ---------------- fc0: in (B,N,nin) -> planes (B,64,N) ----------------
__global__ void k_fc0(const float* __restrict__ in, const float* __restrict__ w,
                      const float* __restrict__ bias, float* __restrict__ out, int N, int nin) {
    int b = blockIdx.y;
    int x = blockIdx.x * 256 + threadIdx.x;
    float xi[3];
    for (int i = 0; i < nin; ++i) xi[i] = in[((size_t)b * N + x) * nin + i];
    float* ob = out + (size_t)b * 64 * N;
    for (int c = 0; c < 64; ++c) {
        float a = bias[c];
        for (int i = 0; i < nin; ++i) a += w[c * nin + i] * xi[i];
        ob[(size_t)c * N + x] = a;
    }
}

// ---------------- analysis: partial[b][chunk][i][col], col<32: sum ch*w*cos,
//                  32..63: sum ch*w*sin, 64: sum ch*w  (stride 66) ----------------
__global__ __launch_bounds__(256) void k_analysis(const float* __restrict__ ch, const float* __restrict__ nw,
                                                  const float* __restrict__ bases, float* __restrict__ partial,
                                                  int N, int nch) {
    int b = blockIdx.y;
    int chunk = blockIdx.x;
    int tid = threadIdx.x;
    int xlen = N / nch;
    __shared__ float chW[64][68];  // [xx][i]
    __shared__ float bt[64][68];   // [xx][k]
    const float* chb = ch + (size_t)b * 64 * N;
    const float* bb = bases + (size_t)b * 64 * N;
    const float* wb = nw + (size_t)b * N;
    int ti = tid >> 4, tk = tid & 15;
    float acc[4][4] = {};
    float acc0[4] = {};
    int xend = (chunk + 1) * xlen;
    for (int x0 = chunk * xlen; x0 < xend; x0 += 64) {
        __syncthreads();
        #pragma unroll
        for (int r = 0; r < 4; ++r) {
            int flat = tid + 256 * r;
            int i = flat >> 4, xq = flat & 15;
            float4 c4 = *(const float4*)(chb + (size_t)i * N + x0 + xq * 4);
            float4 w4 = *(const float4*)(wb + x0 + xq * 4);
            chW[xq * 4 + 0][i] = c4.x * w4.x;
            chW[xq * 4 + 1][i] = c4.y * w4.y;
            chW[xq * 4 + 2][i] = c4.z * w4.z;
            chW[xq * 4 + 3][i] = c4.w * w4.w;
            float4 b4 = *(const float4*)(bb + (size_t)i * N + x0 + xq * 4);
            bt[xq * 4 + 0][i] = b4.x;
            bt[xq * 4 + 1][i] = b4.y;
            bt[xq * 4 + 2][i] = b4.z;
            bt[xq * 4 + 3][i] = b4.w;
        }
        __syncthreads();
        for (int xx = 0; xx < 64; ++xx) {
            float4 a4 = *(const float4*)&chW[xx][ti * 4];
            float4 b4 = *(const float4*)&bt[xx][tk * 4];
            float av[4] = {a4.x, a4.y, a4.z, a4.w};
            float bv[4] = {b4.x, b4.y, b4.z, b4.w};
            #pragma unroll
            for (int ii = 0; ii < 4; ++ii)
                #pragma unroll
                for (int jj = 0; jj < 4; ++jj)
                    acc[ii][jj] += av[ii] * bv[jj];
            if (tk == 0) {
                acc0[0] += av[0]; acc0[1] += av[1]; acc0[2] += av[2]; acc0[3] += av[3];
            }
        }
    }
    float* pb = partial + (size_t)(b * nch + chunk) * 64 * 66;
    #pragma unroll
    for (int ii = 0; ii < 4; ++ii)
        #pragma unroll
        for (int jj = 0; jj < 4; ++jj)
            pb[(ti * 4 + ii) * 66 + tk * 4 + jj] = acc[ii][jj];
    if (tk == 0) {
        #pragma unroll
        for (int ii = 0; ii < 4; ++ii) pb[(ti * 4 + ii) * 66 + 64] = acc0[ii];
    }
}

// ---------------- reduce partials over chunks -> mom[b][i][col] stride 66 ----------------
__global__ void k_reduce(const float* __restrict__ partial, float* __restrict__ mom, int nch) {
    int b = blockIdx.x;
    for (int e = threadIdx.x; e < 64 * 65; e += 256) {
        int row = e / 65, col = e % 65;
        float s = 0.f;
        for (int c = 0; c < nch; ++c)
            s += partial[(size_t)((b * nch + c) * 64 + row) * 66 + col];
        mom[((size_t)b * 64 + row) * 66 + col] = s;
    }
}

// ---------------- build fused synthesis weights W[b][o][132]:
// cols 0..31: 2*fc_tot, 32..63: -2*fs_tot, 64..127: ws_w, 128: f0_tot + ws_b ----------------
__global__ void k_buildW(const float* __restrict__ momu, const float* __restrict__ momv,
                         const float* __restrict__ ewc, const float* __restrict__ ews, const float* __restrict__ ew0,
                         const float* __restrict__ uwc, const float* __restrict__ uws, const float* __restrict__ uw0,
                         const float* __restrict__ vwc, const float* __restrict__ vws, const float* __restrict__ vw0,
                         const float* __restrict__ wsuw, const float* __restrict__ wsub,
                         const float* __restrict__ wsvw, const float* __restrict__ wsvb,
                         float* __restrict__ Wu, float* __restrict__ Wv, int do_v) {
    int b = blockIdx.y, j = blockIdx.x, o = threadIdx.x;
    const float* mu = momu + (size_t)b * 64 * 66;
    const float* mv = momv + (size_t)b * 64 * 66;
    float* Wub = Wu + (size_t)b * 64 * 132;
    float* Wvb = Wv + (size_t)b * 64 * 132;
    if (j < 32) {
        int k = j;
        float fcu = 0, fsu = 0, fcv = 0, fsv = 0;
        for (int i = 0; i < 64; ++i) {
            float Scv = mv[i * 66 + k], Ssv = mv[i * 66 + 32 + k];
            float Scu = mu[i * 66 + k], Ssu = mu[i * 66 + 32 + k];
            int wi = (i * 64 + o) * 32 + k;
            float ec = ewc[wi], es = ews[wi];
            float uc = uwc[wi], us = uws[wi];
            // x_c = Sc, x_s = -Ss
            // f_c = x_c*wc - x_s*ws = Sc*wc + Ss*ws
            // f_s = x_s*wc + x_c*ws = -Ss*wc + Sc*ws
            fcu += Scv * ec + Ssv * es + Scu * uc + Ssu * us;
            fsu += Scv * es - Ssv * ec + Scu * us - Ssu * uc;
            if (do_v) {
                float vc = vwc[wi], vs = vws[wi];
                fcv += Scv * vc + Ssv * vs;
                fsv += Scv * vs - Ssv * vc;
            }
        }
        Wub[o * 132 + k] = 2.f * fcu;
        Wub[o * 132 + 32 + k] = -2.f * fsu;
        if (do_v) {
            Wvb[o * 132 + k] = 2.f * fcv;
            Wvb[o * 132 + 32 + k] = -2.f * fsv;
        }
    } else {
        for (int c = 0; c < 64; ++c) Wub[o * 132 + 64 + c] = wsuw[o * 64 + c];
        float f0u = 0;
        for (int i = 0; i < 64; ++i)
            f0u += mv[i * 66 + 64] * ew0[i * 64 + o] + mu[i * 66 + 64] * uw0[i * 64 + o];
        Wub[o * 132 + 128] = f0u + wsub[o];
        if (do_v) {
            for (int c = 0; c < 64; ++c) Wvb[o * 132 + 64 + c] = wsvw[o * 64 + c];
            float f0v = 0;
            for (int i = 0; i < 64; ++i) f0v += mv[i * 66 + 64] * vw0[i * 64 + o];
            Wvb[o * 132 + 128] = f0v + wsvb[o];
        }
    }
}

// ---------------- synthesis: out[b][o][x] = act(W[b][o][:] . F[:, x])
// F rows: 0..63 bases planes, 64..127 current channel planes, 128: 1
// In-place safe: phases are column-disjoint; two barriers per phase enforce
// all-reads-before-any-write within the block (wavefront skew race fix).
__global__ __launch_bounds__(256) void k_synth(const float* __restrict__ W, const float* __restrict__ A1,
                                               const float* A2, float* out, int N, int act) {
    int b = blockIdx.y, blk = blockIdx.x, tid = threadIdx.x;
    __shared__ float Wl[64][132];
    for (int idx = tid; idx < 64 * 132; idx += 256) {
        int row = idx / 132, col = idx % 132;
        if (col < 129) Wl[row][col] = W[((size_t)b * 64 + row) * 132 + col];
    }
    __syncthreads();
    int og = tid >> 4, xg = tid & 15;
    const float* A1b = A1 + (size_t)b * 64 * N;
    const float* A2b = A2 + (size_t)b * 64 * N;
    float* ob = out + (size_t)b * 64 * N;
    for (int p = 0; p < 8; ++p) {
        int x = blk * 512 + p * 64 + xg * 4;
        float4 acc[4];
        #pragma unroll
        for (int oi = 0; oi < 4; ++oi) acc[oi] = make_float4(0.f, 0.f, 0.f, 0.f);
        for (int j = 0; j < 64; j += 4) {
            float4 f0 = *(const float4*)(A1b + (size_t)(j + 0) * N + x);
            float4 f1 = *(const float4*)(A1b + (size_t)(j + 1) * N + x);
            float4 f2 = *(const float4*)(A1b + (size_t)(j + 2) * N + x);
            float4 f3 = *(const float4*)(A1b + (size_t)(j + 3) * N + x);
            #pragma unroll
            for (int oi = 0; oi < 4; ++oi) {
                float4 w4 = *(const float4*)&Wl[og * 4 + oi][j];
                acc[oi].x += w4.x * f0.x + w4.y * f1.x + w4.z * f2.x + w4.w * f3.x;
                acc[oi].y += w4.x * f0.y + w4.y * f1.y + w4.z * f2.y + w4.w * f3.y;
                acc[oi].z += w4.x * f0.z + w4.y * f1.z + w4.z * f2.z + w4.w * f3.z;
                acc[oi].w += w4.x * f0.w + w4.y * f1.w + w4.z * f2.w + w4.w * f3.w;
            }
        }
        for (int j = 0; j < 64; j += 4) {
            float4 f0 = *(const float4*)(A2b + (size_t)(j + 0) * N + x);
            float4 f1 = *(const float4*)(A2b + (size_t)(j + 1) * N + x);
            float4 f2 = *(const float4*)(A2b + (size_t)(j + 2) * N + x);
            float4 f3 = *(const float4*)(A2b + (size_t)(j + 3) * N + x);
            #pragma unroll
            for (int oi = 0; oi < 4; ++oi) {
                float4 w4 = *(const float4*)&Wl[og * 4 + oi][64 + j];
                acc[oi].x += w4.x * f0.x + w4.y * f1.x + w4.z * f2.x + w4.w * f3.x;
                acc[oi].y += w4.x * f0.y + w4.y * f1.y + w4.z * f2.y + w4.w * f3.y;
                acc[oi].z += w4.x * f0.z + w4.y * f1.z + w4.z * f2.z + w4.w * f3.z;
                acc[oi].w += w4.x * f0.w + w4.y * f1.w + w4.z * f2.w + w4.w * f3.w;
            }
        }
        // all reads of this phase's columns complete before any thread writes them
        __syncthreads();
        #pragma unroll
        for (int oi = 0; oi < 4; ++oi) {
            float wc = Wl[og * 4 + oi][128];
            float4 v = acc[oi];
            v.x += wc; v.y += wc; v.z += wc; v.w += wc;
            if (act) {
                v.x = gelu_f(v.x); v.y = gelu_f(v.y);
                v.z = gelu_f(v.z); v.w = gelu_f(v.w);
            }
            *(float4*)(ob + (size_t)(og * 4 + oi) * N + x) = v;
        }
        // no thread may advance to next phase's reads until these writes land
        __syncthreads();
    }
}

// ---------------- fc1 (gelu) + fc2 fused ----------------
__global__ __launch_bounds__(256) void k_fc12(const float* __restrict__ u, const float* __restrict__ w1,
                                              const float* __restrict__ b1, const float* __restrict__ w2,
                                              const float* __restrict__ b2, float* __restrict__ out, int N) {
    int b = blockIdx.y, blk = blockIdx.x, tid = threadIdx.x;
    int fg = tid >> 4, xg = tid & 15;
    __shared__ float red[16][16][4];
    const float* ub = u + (size_t)b * 64 * N;
    int x = blk * 64 + xg * 4;
    float acc[8][4] = {};
    for (int c = 0; c < 64; ++c) {
        float4 u4 = *(const float4*)(ub + (size_t)c * N + x);
        #pragma unroll
        for (int ff = 0; ff < 8; ++ff) {
            float wv = w1[(fg * 8 + ff) * 64 + c];
            acc[ff][0] += wv * u4.x;
            acc[ff][1] += wv * u4.y;
            acc[ff][2] += wv * u4.z;
            acc[ff][3] += wv * u4.w;
        }
    }
    float po[4] = {};
    #pragma unroll
    for (int ff = 0; ff < 8; ++ff) {
        int f = fg * 8 + ff;
        float bb = b1[f], w2v = w2[f];
        #pragma unroll
        for (int xi = 0; xi < 4; ++xi) po[xi] += w2v * gelu_f(acc[ff][xi] + bb);
    }
    #pragma unroll
    for (int xi = 0; xi < 4; ++xi) red[fg][xg][xi] = po[xi];
    __syncthreads();
    if (tid < 64) {
        int xg2 = tid >> 2, xi = tid & 3;
        float s = b2[0];
        for (int g = 0; g < 16; ++g) s += red[g][xg2][xi];
        out[(size_t)b * N + blk * 64 + xg2 * 4 + xi] = s;
    }
}

extern "C" void kernel_launch(void* const* d_in, const int* in_sizes, int n_in,
                              void* d_out, int out_size, void* d_ws, size_t ws_size,
                              hipStream_t stream) {
    const float* u_in = (const float*)d_in[0];
    const float* v_in = (const float*)d_in[1];
    const float* nodes_u = (const float*)d_in[3];
    const float* nodes_v = (const float*)d_in[4];
    const float* nwu = (const float*)d_in[5];
    const float* nwv = (const float*)d_in[6];
    const float* modes = (const float*)d_in[7];
    const float* latent = (const float*)d_in[8];
    const float* fc0uw = (const float*)d_in[9];
    const float* fc0ub = (const float*)d_in[10];
    const float* fc0vw = (const float*)d_in[11];
    const float* fc0vb = (const float*)d_in[12];
    const float* ewc = (const float*)d_in[13];
    const float* ews = (const float*)d_in[14];
    const float* ew0 = (const float*)d_in[15];
    const float* uwc = (const float*)d_in[16];
    const float* uws = (const float*)d_in[17];
    const float* uw0 = (const float*)d_in[18];
    const float* vwc = (const float*)d_in[19];
    const float* vws = (const float*)d_in[20];
    const float* vw0 = (const float*)d_in[21];
    const float* wsuw = (const float*)d_in[22];
    const float* wsub = (const float*)d_in[23];
    const float* wsvw = (const float*)d_in[24];
    const float* wsvb = (const float*)d_in[25];
    const float* fc1w = (const float*)d_in[26];
    const float* fc1b = (const float*)d_in[27];
    const float* fc2w = (const float*)d_in[28];
    const float* fc2b = (const float*)d_in[29];
    float* out = (float*)d_out;

    const int B = 4, NU = 65536, NV = 16384;
    float* ws = (float*)d_ws;
    float* bases_u = ws;
    float* bases_v = bases_u + (size_t)B * 64 * NU;
    float* ubuf = bases_v + (size_t)B * 64 * NV;
    float* vbuf = ubuf + (size_t)B * 64 * NU;
    float* partial = vbuf + (size_t)B * 64 * NV;
    float* momu = partial + (size_t)B * 64 * 64 * 66;
    float* momv = momu + B * 64 * 66;
    float* Wu = momv + B * 64 * 66;
    float* Wv = Wu + B * 64 * 132;

    k_bases<<<dim3(NU / 256, B), 256, 0, stream>>>(nodes_u, modes, latent, bases_u, NU);
    k_bases<<<dim3(NV / 256, B), 256, 0, stream>>>(nodes_v, modes, latent, bases_v, NV);
    k_fc0<<<dim3(NU / 256, B), 256, 0, stream>>>(u_in, fc0uw, fc0ub, ubuf, NU, 2);
    k_fc0<<<dim3(NV / 256, B), 256, 0, stream>>>(v_in, fc0vw, fc0vb, vbuf, NV, 3);

    for (int l = 0; l < 3; ++l) {
        int do_v = (l < 2) ? 1 : 0;
        k_analysis<<<dim3(64, B), 256, 0, stream>>>(ubuf, nwu, bases_u, partial, NU, 64);
        k_reduce<<<B, 256, 0, stream>>>(partial, momu, 64);
        k_analysis<<<dim3(16, B), 256, 0, stream>>>(vbuf, nwv, bases_v, partial, NV, 16);
        k_reduce<<<B, 256, 0, stream>>>(partial, momv, 16);
        k_buildW<<<dim3(33, B), 64, 0, stream>>>(momu, momv,
            ewc + (size_t)l * 64 * 64 * 32, ews + (size_t)l * 64 * 64 * 32, ew0 + (size_t)l * 64 * 64,
            uwc + (size_t)l * 64 * 64 * 32, uws + (size_t)l * 64 * 64 * 32, uw0 + (size_t)l * 64 * 64,
            vwc + (size_t)l * 64 * 64 * 32, vws + (size_t)l * 64 * 64 * 32, vw0 + (size_t)l * 64 * 64,
            wsuw + l * 64 * 64, wsub + l * 64, wsvw + l * 64 * 64, wsvb + l * 64,
            Wu, Wv, do_v);
        k_synth<<<dim3(NU / 512, B), 256, 0, stream>>>(Wu, bases_u, ubuf, ubuf, NU, do_v);
        if (do_v)
            k_synth<<<dim3(NV / 512, B), 256, 0, stream>>>(Wv, bases_v, vbuf, vbuf, NV, 1);
    }
    k_fc12<<<dim3(NU / 64, B), 256, 0, stream>>>(ubuf, fc1w, fc1b, fc2w, fc2b, out, NU);
}

// Round 3
// 1370.949 us; speedup vs baseline: 1.7005x; 1.7005x over previous
//
#include <hip/hip_runtime.h>
#include <math.h>

#define PI2 6.283185307179586f

__device__ __forceinline__ float gelu_f(float x) {
    return 0.5f * x * (1.0f + erff(x * 0.7071067811865476f));
}

// ---------------- bases: planes [b][k][x] k<32: cos, 32..63: sin ----------------
__global__ void k_bases(const float* __restrict__ nodes, const float* __restrict__ modes,
                        const float* __restrict__ latent, float* __restrict__ out, int N) {
    int b = blockIdx.y;
    int x = blockIdx.x * 256 + threadIdx.x;
    float s0 = 0.5f + 1.5f / (1.0f + expf(-latent[0]));
    float s1 = 0.5f + 1.5f / (1.0f + expf(-latent[1]));
    float n0 = nodes[((size_t)b * N + x) * 2 + 0];
    float n1 = nodes[((size_t)b * N + x) * 2 + 1];
    float* ob = out + (size_t)b * 64 * N;
    for (int k = 0; k < 32; ++k) {
        float m0 = modes[k * 2 + 0] * s0;
        float m1 = modes[k * 2 + 1] * s1;
        float t = PI2 * (n0 * m0 + n1 * m1);
        float s, c;
        sincosf(t, &s, &c);
        ob[(size_t)k * N + x] = c;
        ob[(size_t)(32 + k) * N + x] = s;
    }
}

// ---------------- fc0: in (B,N,nin) -> planes (B,64,N) ----------------
__global__ void k_fc0(const float* __restrict__ in, const float* __restrict__ w,
                      const float* __restrict__ bias, float* __restrict__ out, int N, int nin) {
    int b = blockIdx.y;
    int x = blockIdx.x * 256 + threadIdx.x;
    float xi[3];
    for (int i = 0; i < nin; ++i) xi[i] = in[((size_t)b * N + x) * nin + i];
    float* ob = out + (size_t)b * 64 * N;
    for (int c = 0; c < 64; ++c) {
        float a = bias[c];
        for (int i = 0; i < nin; ++i) a += w[c * nin + i] * xi[i];
        ob[(size_t)c * N + x] = a;
    }
}

// ---------------- analysis: partial[b][chunk][i][col], col<32: sum ch*w*cos,
//                  32..63: sum ch*w*sin, 64: sum ch*w  (stride 66) ----------------
__global__ __launch_bounds__(256) void k_analysis(const float* __restrict__ ch, const float* __restrict__ nw,
                                                  const float* __restrict__ bases, float* __restrict__ partial,
                                                  int N, int nch) {
    int b = blockIdx.y;
    int chunk = blockIdx.x;
    int tid = threadIdx.x;
    int xlen = N / nch;
    __shared__ float chW[64][68];  // [xx][i]
    __shared__ float bt[64][68];   // [xx][k]
    const float* chb = ch + (size_t)b * 64 * N;
    const float* bb = bases + (size_t)b * 64 * N;
    const float* wb = nw + (size_t)b * N;
    int ti = tid >> 4, tk = tid & 15;
    float acc[4][4] = {};
    float acc0[4] = {};
    int xend = (chunk + 1) * xlen;
    for (int x0 = chunk * xlen; x0 < xend; x0 += 64) {
        __syncthreads();
        #pragma unroll
        for (int r = 0; r < 4; ++r) {
            int flat = tid + 256 * r;
            int i = flat >> 4, xq = flat & 15;
            float4 c4 = *(const float4*)(chb + (size_t)i * N + x0 + xq * 4);
            float4 w4 = *(const float4*)(wb + x0 + xq * 4);
            chW[xq * 4 + 0][i] = c4.x * w4.x;
            chW[xq * 4 + 1][i] = c4.y * w4.y;
            chW[xq * 4 + 2][i] = c4.z * w4.z;
            chW[xq * 4 + 3][i] = c4.w * w4.w;
            float4 b4 = *(const float4*)(bb + (size_t)i * N + x0 + xq * 4);
            bt[xq * 4 + 0][i] = b4.x;
            bt[xq * 4 + 1][i] = b4.y;
            bt[xq * 4 + 2][i] = b4.z;
            bt[xq * 4 + 3][i] = b4.w;
        }
        __syncthreads();
        for (int xx = 0; xx < 64; ++xx) {
            float4 a4 = *(const float4*)&chW[xx][ti * 4];
            float4 b4 = *(const float4*)&bt[xx][tk * 4];
            float av[4] = {a4.x, a4.y, a4.z, a4.w};
            float bv[4] = {b4.x, b4.y, b4.z, b4.w};
            #pragma unroll
            for (int ii = 0; ii < 4; ++ii)
                #pragma unroll
                for (int jj = 0; jj < 4; ++jj)
                    acc[ii][jj] += av[ii] * bv[jj];
            if (tk == 0) {
                acc0[0] += av[0]; acc0[1] += av[1]; acc0[2] += av[2]; acc0[3] += av[3];
            }
        }
    }
    float* pb = partial + (size_t)(b * nch + chunk) * 64 * 66;
    #pragma unroll
    for (int ii = 0; ii < 4; ++ii)
        #pragma unroll
        for (int jj = 0; jj < 4; ++jj)
            pb[(ti * 4 + ii) * 66 + tk * 4 + jj] = acc[ii][jj];
    if (tk == 0) {
        #pragma unroll
        for (int ii = 0; ii < 4; ++ii) pb[(ti * 4 + ii) * 66 + 64] = acc0[ii];
    }
}

// ---------------- reduce partials over chunks -> mom[b][i][col] stride 66
// one thread per output element; nch independent strided loads pipelined ----------------
__global__ void k_reduce(const float* __restrict__ partial, float* __restrict__ mom, int nch) {
    int b = blockIdx.y;
    int e = blockIdx.x * 256 + threadIdx.x;
    if (e >= 64 * 65) return;
    int row = e / 65, col = e % 65;
    const float* p = partial + ((size_t)(b * nch) * 64 + row) * 66 + col;
    float s = 0.f;
    #pragma unroll 4
    for (int c = 0; c < nch; ++c)
        s += p[(size_t)c * 64 * 66];
    mom[((size_t)b * 64 + row) * 66 + col] = s;
}

// ---------------- build fused synthesis weights W[b][o][132]:
// cols 0..31: 2*fc_tot, 32..63: -2*fs_tot, 64..127: ws_w, 128: f0_tot + ws_b ----------------
__global__ void k_buildW(const float* __restrict__ momu, const float* __restrict__ momv,
                         const float* __restrict__ ewc, const float* __restrict__ ews, const float* __restrict__ ew0,
                         const float* __restrict__ uwc, const float* __restrict__ uws, const float* __restrict__ uw0,
                         const float* __restrict__ vwc, const float* __restrict__ vws, const float* __restrict__ vw0,
                         const float* __restrict__ wsuw, const float* __restrict__ wsub,
                         const float* __restrict__ wsvw, const float* __restrict__ wsvb,
                         float* __restrict__ Wu, float* __restrict__ Wv, int do_v) {
    int b = blockIdx.y, j = blockIdx.x, o = threadIdx.x;
    const float* mu = momu + (size_t)b * 64 * 66;
    const float* mv = momv + (size_t)b * 64 * 66;
    float* Wub = Wu + (size_t)b * 64 * 132;
    float* Wvb = Wv + (size_t)b * 64 * 132;
    if (j < 32) {
        int k = j;
        float fcu = 0, fsu = 0, fcv = 0, fsv = 0;
        for (int i = 0; i < 64; ++i) {
            float Scv = mv[i * 66 + k], Ssv = mv[i * 66 + 32 + k];
            float Scu = mu[i * 66 + k], Ssu = mu[i * 66 + 32 + k];
            int wi = (i * 64 + o) * 32 + k;
            float ec = ewc[wi], es = ews[wi];
            float uc = uwc[wi], us = uws[wi];
            // x_c = Sc, x_s = -Ss
            // f_c = x_c*wc - x_s*ws = Sc*wc + Ss*ws
            // f_s = x_s*wc + x_c*ws = -Ss*wc + Sc*ws
            fcu += Scv * ec + Ssv * es + Scu * uc + Ssu * us;
            fsu += Scv * es - Ssv * ec + Scu * us - Ssu * uc;
            if (do_v) {
                float vc = vwc[wi], vs = vws[wi];
                fcv += Scv * vc + Ssv * vs;
                fsv += Scv * vs - Ssv * vc;
            }
        }
        Wub[o * 132 + k] = 2.f * fcu;
        Wub[o * 132 + 32 + k] = -2.f * fsu;
        if (do_v) {
            Wvb[o * 132 + k] = 2.f * fcv;
            Wvb[o * 132 + 32 + k] = -2.f * fsv;
        }
    } else {
        for (int c = 0; c < 64; ++c) Wub[o * 132 + 64 + c] = wsuw[o * 64 + c];
        float f0u = 0;
        for (int i = 0; i < 64; ++i)
            f0u += mv[i * 66 + 64] * ew0[i * 64 + o] + mu[i * 66 + 64] * uw0[i * 64 + o];
        Wub[o * 132 + 128] = f0u + wsub[o];
        if (do_v) {
            for (int c = 0; c < 64; ++c) Wvb[o * 132 + 64 + c] = wsvw[o * 64 + c];
            float f0v = 0;
            for (int i = 0; i < 64; ++i) f0v += mv[i * 66 + 64] * vw0[i * 64 + o];
            Wvb[o * 132 + 128] = f0v + wsvb[o];
        }
    }
}

// ---------------- synthesis: out[b][o][x] = act(W[b][o][:] . F[:, x])
// F rows: 0..63 bases planes, 64..127 current channel planes, 128: 1
// In-place safe: phases are column-disjoint; two barriers per phase enforce
// all-reads-before-any-write within the block (wavefront skew race fix).
__global__ __launch_bounds__(256) void k_synth(const float* __restrict__ W, const float* __restrict__ A1,
                                               const float* A2, float* out, int N, int act) {
    int b = blockIdx.y, blk = blockIdx.x, tid = threadIdx.x;
    __shared__ float Wl[64][132];
    for (int idx = tid; idx < 64 * 132; idx += 256) {
        int row = idx / 132, col = idx % 132;
        if (col < 129) Wl[row][col] = W[((size_t)b * 64 + row) * 132 + col];
    }
    __syncthreads();
    int og = tid >> 4, xg = tid & 15;
    const float* A1b = A1 + (size_t)b * 64 * N;
    const float* A2b = A2 + (size_t)b * 64 * N;
    float* ob = out + (size_t)b * 64 * N;
    for (int p = 0; p < 8; ++p) {
        int x = blk * 512 + p * 64 + xg * 4;
        float4 acc[4];
        #pragma unroll
        for (int oi = 0; oi < 4; ++oi) acc[oi] = make_float4(0.f, 0.f, 0.f, 0.f);
        for (int j = 0; j < 64; j += 4) {
            float4 f0 = *(const float4*)(A1b + (size_t)(j + 0) * N + x);
            float4 f1 = *(const float4*)(A1b + (size_t)(j + 1) * N + x);
            float4 f2 = *(const float4*)(A1b + (size_t)(j + 2) * N + x);
            float4 f3 = *(const float4*)(A1b + (size_t)(j + 3) * N + x);
            #pragma unroll
            for (int oi = 0; oi < 4; ++oi) {
                float4 w4 = *(const float4*)&Wl[og * 4 + oi][j];
                acc[oi].x += w4.x * f0.x + w4.y * f1.x + w4.z * f2.x + w4.w * f3.x;
                acc[oi].y += w4.x * f0.y + w4.y * f1.y + w4.z * f2.y + w4.w * f3.y;
                acc[oi].z += w4.x * f0.z + w4.y * f1.z + w4.z * f2.z + w4.w * f3.z;
                acc[oi].w += w4.x * f0.w + w4.y * f1.w + w4.z * f2.w + w4.w * f3.w;
            }
        }
        for (int j = 0; j < 64; j += 4) {
            float4 f0 = *(const float4*)(A2b + (size_t)(j + 0) * N + x);
            float4 f1 = *(const float4*)(A2b + (size_t)(j + 1) * N + x);
            float4 f2 = *(const float4*)(A2b + (size_t)(j + 2) * N + x);
            float4 f3 = *(const float4*)(A2b + (size_t)(j + 3) * N + x);
            #pragma unroll
            for (int oi = 0; oi < 4; ++oi) {
                float4 w4 = *(const float4*)&Wl[og * 4 + oi][64 + j];
                acc[oi].x += w4.x * f0.x + w4.y * f1.x + w4.z * f2.x + w4.w * f3.x;
                acc[oi].y += w4.x * f0.y + w4.y * f1.y + w4.z * f2.y + w4.w * f3.y;
                acc[oi].z += w4.x * f0.z + w4.y * f1.z + w4.z * f2.z + w4.w * f3.z;
                acc[oi].w += w4.x * f0.w + w4.y * f1.w + w4.z * f2.w + w4.w * f3.w;
            }
        }
        // all reads of this phase's columns complete before any thread writes them
        __syncthreads();
        #pragma unroll
        for (int oi = 0; oi < 4; ++oi) {
            float wc = Wl[og * 4 + oi][128];
            float4 v = acc[oi];
            v.x += wc; v.y += wc; v.z += wc; v.w += wc;
            if (act) {
                v.x = gelu_f(v.x); v.y = gelu_f(v.y);
                v.z = gelu_f(v.z); v.w = gelu_f(v.w);
            }
            *(float4*)(ob + (size_t)(og * 4 + oi) * N + x) = v;
        }
        // no thread may advance to next phase's reads until these writes land
        __syncthreads();
    }
}

// ---------------- fc1 (gelu) + fc2 fused ----------------
__global__ __launch_bounds__(256) void k_fc12(const float* __restrict__ u, const float* __restrict__ w1,
                                              const float* __restrict__ b1, const float* __restrict__ w2,
                                              const float* __restrict__ b2, float* __restrict__ out, int N) {
    int b = blockIdx.y, blk = blockIdx.x, tid = threadIdx.x;
    int fg = tid >> 4, xg = tid & 15;
    __shared__ float red[16][16][4];
    const float* ub = u + (size_t)b * 64 * N;
    int x = blk * 64 + xg * 4;
    float acc[8][4] = {};
    for (int c = 0; c < 64; ++c) {
        float4 u4 = *(const float4*)(ub + (size_t)c * N + x);
        #pragma unroll
        for (int ff = 0; ff < 8; ++ff) {
            float wv = w1[(fg * 8 + ff) * 64 + c];
            acc[ff][0] += wv * u4.x;
            acc[ff][1] += wv * u4.y;
            acc[ff][2] += wv * u4.z;
            acc[ff][3] += wv * u4.w;
        }
    }
    float po[4] = {};
    #pragma unroll
    for (int ff = 0; ff < 8; ++ff) {
        int f = fg * 8 + ff;
        float bb = b1[f], w2v = w2[f];
        #pragma unroll
        for (int xi = 0; xi < 4; ++xi) po[xi] += w2v * gelu_f(acc[ff][xi] + bb);
    }
    #pragma unroll
    for (int xi = 0; xi < 4; ++xi) red[fg][xg][xi] = po[xi];
    __syncthreads();
    if (tid < 64) {
        int xg2 = tid >> 2, xi = tid & 3;
        float s = b2[0];
        for (int g = 0; g < 16; ++g) s += red[g][xg2][xi];
        out[(size_t)b * N + blk * 64 + xg2 * 4 + xi] = s;
    }
}

extern "C" void kernel_launch(void* const* d_in, const int* in_sizes, int n_in,
                              void* d_out, int out_size, void* d_ws, size_t ws_size,
                              hipStream_t stream) {
    const float* u_in = (const float*)d_in[0];
    const float* v_in = (const float*)d_in[1];
    const float* nodes_u = (const float*)d_in[3];
    const float* nodes_v = (const float*)d_in[4];
    const float* nwu = (const float*)d_in[5];
    const float* nwv = (const float*)d_in[6];
    const float* modes = (const float*)d_in[7];
    const float* latent = (const float*)d_in[8];
    const float* fc0uw = (const float*)d_in[9];
    const float* fc0ub = (const float*)d_in[10];
    const float* fc0vw = (const float*)d_in[11];
    const float* fc0vb = (const float*)d_in[12];
    const float* ewc = (const float*)d_in[13];
    const float* ews = (const float*)d_in[14];
    const float* ew0 = (const float*)d_in[15];
    const float* uwc = (const float*)d_in[16];
    const float* uws = (const float*)d_in[17];
    const float* uw0 = (const float*)d_in[18];
    const float* vwc = (const float*)d_in[19];
    const float* vws = (const float*)d_in[20];
    const float* vw0 = (const float*)d_in[21];
    const float* wsuw = (const float*)d_in[22];
    const float* wsub = (const float*)d_in[23];
    const float* wsvw = (const float*)d_in[24];
    const float* wsvb = (const float*)d_in[25];
    const float* fc1w = (const float*)d_in[26];
    const float* fc1b = (const float*)d_in[27];
    const float* fc2w = (const float*)d_in[28];
    const float* fc2b = (const float*)d_in[29];
    float* out = (float*)d_out;

    const int B = 4, NU = 65536, NV = 16384;
    float* ws = (float*)d_ws;
    float* bases_u = ws;
    float* bases_v = bases_u + (size_t)B * 64 * NU;
    float* ubuf = bases_v + (size_t)B * 64 * NV;
    float* vbuf = ubuf + (size_t)B * 64 * NU;
    float* partial = vbuf + (size_t)B * 64 * NV;
    float* momu = partial + (size_t)B * 64 * 64 * 66;
    float* momv = momu + B * 64 * 66;
    float* Wu = momv + B * 64 * 66;
    float* Wv = Wu + B * 64 * 132;

    k_bases<<<dim3(NU / 256, B), 256, 0, stream>>>(nodes_u, modes, latent, bases_u, NU);
    k_bases<<<dim3(NV / 256, B), 256, 0, stream>>>(nodes_v, modes, latent, bases_v, NV);
    k_fc0<<<dim3(NU / 256, B), 256, 0, stream>>>(u_in, fc0uw, fc0ub, ubuf, NU, 2);
    k_fc0<<<dim3(NV / 256, B), 256, 0, stream>>>(v_in, fc0vw, fc0vb, vbuf, NV, 3);

    for (int l = 0; l < 3; ++l) {
        int do_v = (l < 2) ? 1 : 0;
        k_analysis<<<dim3(64, B), 256, 0, stream>>>(ubuf, nwu, bases_u, partial, NU, 64);
        k_reduce<<<dim3(17, B), 256, 0, stream>>>(partial, momu, 64);
        k_analysis<<<dim3(16, B), 256, 0, stream>>>(vbuf, nwv, bases_v, partial, NV, 16);
        k_reduce<<<dim3(17, B), 256, 0, stream>>>(partial, momv, 16);
        k_buildW<<<dim3(33, B), 64, 0, stream>>>(momu, momv,
            ewc + (size_t)l * 64 * 64 * 32, ews + (size_t)l * 64 * 64 * 32, ew0 + (size_t)l * 64 * 64,
            uwc + (size_t)l * 64 * 64 * 32, uws + (size_t)l * 64 * 64 * 32, uw0 + (size_t)l * 64 * 64,
            vwc + (size_t)l * 64 * 64 * 32, vws + (size_t)l * 64 * 64 * 32, vw0 + (size_t)l * 64 * 64,
            wsuw + l * 64 * 64, wsub + l * 64, wsvw + l * 64 * 64, wsvb + l * 64,
            Wu, Wv, do_v);
        k_synth<<<dim3(NU / 512, B), 256, 0, stream>>>(Wu, bases_u, ubuf, ubuf, NU, do_v);
        if (do_v)
            k_synth<<<dim3(NV / 512, B), 256, 0, stream>>>(Wv, bases_v, vbuf, vbuf, NV, 1);
    }
    k_fc12<<<dim3(NU / 64, B), 256, 0, stream>>>(ubuf, fc1w, fc1b, fc2w, fc2b, out, NU);
}

// Round 4
// 939.274 us; speedup vs baseline: 2.4821x; 1.4596x over previous
//
#include <hip/hip_runtime.h>
#include <math.h>

#define PI2 6.283185307179586f

__device__ __forceinline__ float gelu_f(float x) {
    return 0.5f * x * (1.0f + erff(x * 0.7071067811865476f));
}

// ---------------- bases: planes [b][k][x] k<32: cos, 32..63: sin ----------------
__global__ void k_bases(const float* __restrict__ nodes, const float* __restrict__ modes,
                        const float* __restrict__ latent, float* __restrict__ out, int N) {
    int b = blockIdx.y;
    int x = blockIdx.x * 256 + threadIdx.x;
    float s0 = 0.5f + 1.5f / (1.0f + expf(-latent[0]));
    float s1 = 0.5f + 1.5f / (1.0f + expf(-latent[1]));
    float n0 = nodes[((size_t)b * N + x) * 2 + 0];
    float n1 = nodes[((size_t)b * N + x) * 2 + 1];
    float* ob = out + (size_t)b * 64 * N;
    for (int k = 0; k < 32; ++k) {
        float m0 = modes[k * 2 + 0] * s0;
        float m1 = modes[k * 2 + 1] * s1;
        float t = PI2 * (n0 * m0 + n1 * m1);
        float s, c;
        sincosf(t, &s, &c);
        ob[(size_t)k * N + x] = c;
        ob[(size_t)(32 + k) * N + x] = s;
    }
}

// ---------------- fc0: in (B,N,nin) -> planes (B,64,N) ----------------
__global__ void k_fc0(const float* __restrict__ in, const float* __restrict__ w,
                      const float* __restrict__ bias, float* __restrict__ out, int N, int nin) {
    int b = blockIdx.y;
    int x = blockIdx.x * 256 + threadIdx.x;
    float xi[3];
    for (int i = 0; i < nin; ++i) xi[i] = in[((size_t)b * N + x) * nin + i];
    float* ob = out + (size_t)b * 64 * N;
    for (int c = 0; c < 64; ++c) {
        float a = bias[c];
        for (int i = 0; i < nin; ++i) a += w[c * nin + i] * xi[i];
        ob[(size_t)c * N + x] = a;
    }
}

// ---------------- analysis: partial[b][chunk][i][col], col<32: sum ch*w*cos,
//                  32..63: sum ch*w*sin, 64: sum ch*w  (stride 66) ----------------
__global__ __launch_bounds__(256) void k_analysis(const float* __restrict__ ch, const float* __restrict__ nw,
                                                  const float* __restrict__ bases, float* __restrict__ partial,
                                                  int N, int nch) {
    int b = blockIdx.y;
    int chunk = blockIdx.x;
    int tid = threadIdx.x;
    int xlen = N / nch;
    __shared__ float chW[64][68];  // [xx][i]
    __shared__ float bt[64][68];   // [xx][k]
    const float* chb = ch + (size_t)b * 64 * N;
    const float* bb = bases + (size_t)b * 64 * N;
    const float* wb = nw + (size_t)b * N;
    int ti = tid >> 4, tk = tid & 15;
    float acc[4][4] = {};
    float acc0[4] = {};
    int xend = (chunk + 1) * xlen;
    for (int x0 = chunk * xlen; x0 < xend; x0 += 64) {
        __syncthreads();
        #pragma unroll
        for (int r = 0; r < 4; ++r) {
            int flat = tid + 256 * r;
            int i = flat >> 4, xq = flat & 15;
            float4 c4 = *(const float4*)(chb + (size_t)i * N + x0 + xq * 4);
            float4 w4 = *(const float4*)(wb + x0 + xq * 4);
            chW[xq * 4 + 0][i] = c4.x * w4.x;
            chW[xq * 4 + 1][i] = c4.y * w4.y;
            chW[xq * 4 + 2][i] = c4.z * w4.z;
            chW[xq * 4 + 3][i] = c4.w * w4.w;
            float4 b4 = *(const float4*)(bb + (size_t)i * N + x0 + xq * 4);
            bt[xq * 4 + 0][i] = b4.x;
            bt[xq * 4 + 1][i] = b4.y;
            bt[xq * 4 + 2][i] = b4.z;
            bt[xq * 4 + 3][i] = b4.w;
        }
        __syncthreads();
        for (int xx = 0; xx < 64; ++xx) {
            float4 a4 = *(const float4*)&chW[xx][ti * 4];
            float4 b4 = *(const float4*)&bt[xx][tk * 4];
            float av[4] = {a4.x, a4.y, a4.z, a4.w};
            float bv[4] = {b4.x, b4.y, b4.z, b4.w};
            #pragma unroll
            for (int ii = 0; ii < 4; ++ii)
                #pragma unroll
                for (int jj = 0; jj < 4; ++jj)
                    acc[ii][jj] += av[ii] * bv[jj];
            if (tk == 0) {
                acc0[0] += av[0]; acc0[1] += av[1]; acc0[2] += av[2]; acc0[3] += av[3];
            }
        }
    }
    float* pb = partial + (size_t)(b * nch + chunk) * 64 * 66;
    #pragma unroll
    for (int ii = 0; ii < 4; ++ii)
        #pragma unroll
        for (int jj = 0; jj < 4; ++jj)
            pb[(ti * 4 + ii) * 66 + tk * 4 + jj] = acc[ii][jj];
    if (tk == 0) {
        #pragma unroll
        for (int ii = 0; ii < 4; ++ii) pb[(ti * 4 + ii) * 66 + 64] = acc0[ii];
    }
}

// ---------------- reduce partials over chunks -> mom[b][i][col] stride 66 ----------------
__global__ void k_reduce(const float* __restrict__ partial, float* __restrict__ mom, int nch) {
    int b = blockIdx.y;
    int e = blockIdx.x * 256 + threadIdx.x;
    if (e >= 64 * 65) return;
    int row = e / 65, col = e % 65;
    const float* p = partial + ((size_t)(b * nch) * 64 + row) * 66 + col;
    float s = 0.f;
    #pragma unroll 4
    for (int c = 0; c < nch; ++c)
        s += p[(size_t)c * 64 * 66];
    mom[((size_t)b * 64 + row) * 66 + col] = s;
}

// ---------------- transpose weight arrays (l,i,o,k) -> (l,k,i,o) for coalesced buildW ----------------
__global__ __launch_bounds__(256) void k_tw(const float* __restrict__ e_c, const float* __restrict__ e_s,
                                            const float* __restrict__ u_c, const float* __restrict__ u_s,
                                            const float* __restrict__ v_c, const float* __restrict__ v_s,
                                            float* __restrict__ oT) {
    int li = blockIdx.x;   // l*64 + i
    int a = blockIdx.y;    // array 0..5
    const float* in;
    switch (a) {
        case 0: in = e_c; break;
        case 1: in = e_s; break;
        case 2: in = u_c; break;
        case 3: in = u_s; break;
        case 4: in = v_c; break;
        default: in = v_s; break;
    }
    float* outp = oT + (size_t)a * 393216;
    int l = li >> 6, i = li & 63;
    __shared__ float t[32][65];
    int tid = threadIdx.x;
    const float* ib = in + (size_t)l * 131072 + (size_t)i * 2048;  // [o][k] 64x32
    #pragma unroll
    for (int r = 0; r < 8; ++r) {
        int e = r * 256 + tid;            // o = e>>5, k = e&31
        t[e & 31][e >> 5] = ib[e];
    }
    __syncthreads();
    float* ob = outp + (size_t)l * 131072 + (size_t)i * 64;
    #pragma unroll
    for (int r = 0; r < 8; ++r) {
        int e = r * 256 + tid;            // k = e>>6, o = e&63
        ob[(size_t)(e >> 6) * 4096 + (e & 63)] = t[e >> 6][e & 63];
    }
}

// ---------------- build fused synthesis weights W[b][o][132] (coalesced, transposed weights) ----------------
__global__ void k_buildW(const float* __restrict__ momu, const float* __restrict__ momv,
                         const float* __restrict__ ecT, const float* __restrict__ esT, const float* __restrict__ ew0,
                         const float* __restrict__ ucT, const float* __restrict__ usT, const float* __restrict__ uw0,
                         const float* __restrict__ vcT, const float* __restrict__ vsT, const float* __restrict__ vw0,
                         const float* __restrict__ wsuw, const float* __restrict__ wsub,
                         const float* __restrict__ wsvw, const float* __restrict__ wsvb,
                         float* __restrict__ Wu, float* __restrict__ Wv, int do_v) {
    int b = blockIdx.y, j = blockIdx.x, o = threadIdx.x;
    const float* mu = momu + (size_t)b * 64 * 66;
    const float* mv = momv + (size_t)b * 64 * 66;
    float* Wub = Wu + (size_t)b * 64 * 132;
    float* Wvb = Wv + (size_t)b * 64 * 132;
    if (j < 32) {
        int k = j;
        const float* ec = ecT + (size_t)k * 4096;
        const float* es = esT + (size_t)k * 4096;
        const float* uc = ucT + (size_t)k * 4096;
        const float* us = usT + (size_t)k * 4096;
        const float* vc = vcT + (size_t)k * 4096;
        const float* vs = vsT + (size_t)k * 4096;
        float fcu = 0, fsu = 0, fcv = 0, fsv = 0;
        for (int i = 0; i < 64; ++i) {
            float Scv = mv[i * 66 + k], Ssv = mv[i * 66 + 32 + k];
            float Scu = mu[i * 66 + k], Ssu = mu[i * 66 + 32 + k];
            int wi = i * 64 + o;
            float e_c = ec[wi], e_s = es[wi];
            float u_c = uc[wi], u_s = us[wi];
            fcu += Scv * e_c + Ssv * e_s + Scu * u_c + Ssu * u_s;
            fsu += Scv * e_s - Ssv * e_c + Scu * u_s - Ssu * u_c;
            if (do_v) {
                float v_c = vc[wi], v_s = vs[wi];
                fcv += Scv * v_c + Ssv * v_s;
                fsv += Scv * v_s - Ssv * v_c;
            }
        }
        Wub[o * 132 + k] = 2.f * fcu;
        Wub[o * 132 + 32 + k] = -2.f * fsu;
        if (do_v) {
            Wvb[o * 132 + k] = 2.f * fcv;
            Wvb[o * 132 + 32 + k] = -2.f * fsv;
        }
    } else {
        for (int c = 0; c < 64; ++c) Wub[o * 132 + 64 + c] = wsuw[o * 64 + c];
        float f0u = 0;
        for (int i = 0; i < 64; ++i)
            f0u += mv[i * 66 + 64] * ew0[i * 64 + o] + mu[i * 66 + 64] * uw0[i * 64 + o];
        Wub[o * 132 + 128] = f0u + wsub[o];
        if (do_v) {
            for (int c = 0; c < 64; ++c) Wvb[o * 132 + 64 + c] = wsvw[o * 64 + c];
            float f0v = 0;
            for (int i = 0; i < 64; ++i) f0v += mv[i * 66 + 64] * vw0[i * 64 + o];
            Wvb[o * 132 + 128] = f0v + wsvb[o];
        }
    }
}

// ---------------- fallback buildW (original weight layout, uncoalesced) ----------------
__global__ void k_buildW_slow(const float* __restrict__ momu, const float* __restrict__ momv,
                              const float* __restrict__ ewc, const float* __restrict__ ews, const float* __restrict__ ew0,
                              const float* __restrict__ uwc, const float* __restrict__ uws, const float* __restrict__ uw0,
                              const float* __restrict__ vwc, const float* __restrict__ vws, const float* __restrict__ vw0,
                              const float* __restrict__ wsuw, const float* __restrict__ wsub,
                              const float* __restrict__ wsvw, const float* __restrict__ wsvb,
                              float* __restrict__ Wu, float* __restrict__ Wv, int do_v) {
    int b = blockIdx.y, j = blockIdx.x, o = threadIdx.x;
    const float* mu = momu + (size_t)b * 64 * 66;
    const float* mv = momv + (size_t)b * 64 * 66;
    float* Wub = Wu + (size_t)b * 64 * 132;
    float* Wvb = Wv + (size_t)b * 64 * 132;
    if (j < 32) {
        int k = j;
        float fcu = 0, fsu = 0, fcv = 0, fsv = 0;
        for (int i = 0; i < 64; ++i) {
            float Scv = mv[i * 66 + k], Ssv = mv[i * 66 + 32 + k];
            float Scu = mu[i * 66 + k], Ssu = mu[i * 66 + 32 + k];
            int wi = (i * 64 + o) * 32 + k;
            float ec = ewc[wi], es = ews[wi];
            float uc = uwc[wi], us = uws[wi];
            fcu += Scv * ec + Ssv * es + Scu * uc + Ssu * us;
            fsu += Scv * es - Ssv * ec + Scu * us - Ssu * uc;
            if (do_v) {
                float vc = vwc[wi], vs = vws[wi];
                fcv += Scv * vc + Ssv * vs;
                fsv += Scv * vs - Ssv * vc;
            }
        }
        Wub[o * 132 + k] = 2.f * fcu;
        Wub[o * 132 + 32 + k] = -2.f * fsu;
        if (do_v) {
            Wvb[o * 132 + k] = 2.f * fcv;
            Wvb[o * 132 + 32 + k] = -2.f * fsv;
        }
    } else {
        for (int c = 0; c < 64; ++c) Wub[o * 132 + 64 + c] = wsuw[o * 64 + c];
        float f0u = 0;
        for (int i = 0; i < 64; ++i)
            f0u += mv[i * 66 + 64] * ew0[i * 64 + o] + mu[i * 66 + 64] * uw0[i * 64 + o];
        Wub[o * 132 + 128] = f0u + wsub[o];
        if (do_v) {
            for (int c = 0; c < 64; ++c) Wvb[o * 132 + 64 + c] = wsvw[o * 64 + c];
            float f0v = 0;
            for (int i = 0; i < 64; ++i) f0v += mv[i * 66 + 64] * vw0[i * 64 + o];
            Wvb[o * 132 + 128] = f0v + wsvb[o];
        }
    }
}

// ---------------- synthesis: out[b][o][x] = act(W[b][o][:] . F[:, x])
// F rows: 0..63 bases planes, 64..127 current channel planes, 128: 1
// In-place safe: phases column-disjoint; two barriers per phase. 256 cols/block. ----------------
__global__ __launch_bounds__(256) void k_synth(const float* __restrict__ W, const float* __restrict__ A1,
                                               const float* A2, float* out, int N, int act) {
    int b = blockIdx.y, blk = blockIdx.x, tid = threadIdx.x;
    __shared__ float Wl[64][132];
    for (int idx = tid; idx < 64 * 132; idx += 256) {
        int row = idx / 132, col = idx % 132;
        if (col < 129) Wl[row][col] = W[((size_t)b * 64 + row) * 132 + col];
    }
    __syncthreads();
    int og = tid >> 4, xg = tid & 15;
    const float* A1b = A1 + (size_t)b * 64 * N;
    const float* A2b = A2 + (size_t)b * 64 * N;
    float* ob = out + (size_t)b * 64 * N;
    for (int p = 0; p < 4; ++p) {
        int x = blk * 256 + p * 64 + xg * 4;
        float4 acc[4];
        #pragma unroll
        for (int oi = 0; oi < 4; ++oi) acc[oi] = make_float4(0.f, 0.f, 0.f, 0.f);
        for (int j = 0; j < 64; j += 4) {
            float4 f0 = *(const float4*)(A1b + (size_t)(j + 0) * N + x);
            float4 f1 = *(const float4*)(A1b + (size_t)(j + 1) * N + x);
            float4 f2 = *(const float4*)(A1b + (size_t)(j + 2) * N + x);
            float4 f3 = *(const float4*)(A1b + (size_t)(j + 3) * N + x);
            #pragma unroll
            for (int oi = 0; oi < 4; ++oi) {
                float4 w4 = *(const float4*)&Wl[og * 4 + oi][j];
                acc[oi].x += w4.x * f0.x + w4.y * f1.x + w4.z * f2.x + w4.w * f3.x;
                acc[oi].y += w4.x * f0.y + w4.y * f1.y + w4.z * f2.y + w4.w * f3.y;
                acc[oi].z += w4.x * f0.z + w4.y * f1.z + w4.z * f2.z + w4.w * f3.z;
                acc[oi].w += w4.x * f0.w + w4.y * f1.w + w4.z * f2.w + w4.w * f3.w;
            }
        }
        for (int j = 0; j < 64; j += 4) {
            float4 f0 = *(const float4*)(A2b + (size_t)(j + 0) * N + x);
            float4 f1 = *(const float4*)(A2b + (size_t)(j + 1) * N + x);
            float4 f2 = *(const float4*)(A2b + (size_t)(j + 2) * N + x);
            float4 f3 = *(const float4*)(A2b + (size_t)(j + 3) * N + x);
            #pragma unroll
            for (int oi = 0; oi < 4; ++oi) {
                float4 w4 = *(const float4*)&Wl[og * 4 + oi][64 + j];
                acc[oi].x += w4.x * f0.x + w4.y * f1.x + w4.z * f2.x + w4.w * f3.x;
                acc[oi].y += w4.x * f0.y + w4.y * f1.y + w4.z * f2.y + w4.w * f3.y;
                acc[oi].z += w4.x * f0.z + w4.y * f1.z + w4.z * f2.z + w4.w * f3.z;
                acc[oi].w += w4.x * f0.w + w4.y * f1.w + w4.z * f2.w + w4.w * f3.w;
            }
        }
        __syncthreads();
        #pragma unroll
        for (int oi = 0; oi < 4; ++oi) {
            float wc = Wl[og * 4 + oi][128];
            float4 v = acc[oi];
            v.x += wc; v.y += wc; v.z += wc; v.w += wc;
            if (act) {
                v.x = gelu_f(v.x); v.y = gelu_f(v.y);
                v.z = gelu_f(v.z); v.w = gelu_f(v.w);
            }
            *(float4*)(ob + (size_t)(og * 4 + oi) * N + x) = v;
        }
        __syncthreads();
    }
}

// ---------------- fc1 (gelu) + fc2 fused, LDS-staged weights + u tile ----------------
__global__ __launch_bounds__(256) void k_fc12(const float* __restrict__ u, const float* __restrict__ w1,
                                              const float* __restrict__ b1, const float* __restrict__ w2,
                                              const float* __restrict__ b2, float* __restrict__ out, int N) {
    int b = blockIdx.y, blk = blockIdx.x, tid = threadIdx.x;
    __shared__ float w1s[128][64];   // 32 KB
    __shared__ float us[64][64];     // 16 KB
    __shared__ float red[16][16][4]; // 4 KB
    // stage w1 (flat 8192 floats, coalesced float4)
    for (int e = tid; e < 2048; e += 256)
        ((float4*)&w1s[0][0])[e] = ((const float4*)w1)[e];
    const float* ub = u + (size_t)b * 64 * N;
    int x0 = blk * 64;
    #pragma unroll
    for (int r = 0; r < 4; ++r) {
        int idx = r * 256 + tid;
        int c = idx >> 4, q = idx & 15;
        *(float4*)&us[c][q * 4] = *(const float4*)(ub + (size_t)c * N + x0 + q * 4);
    }
    __syncthreads();
    int fg = tid >> 4, xg = tid & 15;
    float acc[8][4] = {};
    for (int c = 0; c < 64; c += 4) {
        float4 u0 = *(float4*)&us[c + 0][xg * 4];
        float4 u1 = *(float4*)&us[c + 1][xg * 4];
        float4 u2 = *(float4*)&us[c + 2][xg * 4];
        float4 u3 = *(float4*)&us[c + 3][xg * 4];
        #pragma unroll
        for (int ff = 0; ff < 8; ++ff) {
            float4 w4 = *(float4*)&w1s[fg * 8 + ff][c];
            acc[ff][0] += w4.x * u0.x + w4.y * u1.x + w4.z * u2.x + w4.w * u3.x;
            acc[ff][1] += w4.x * u0.y + w4.y * u1.y + w4.z * u2.y + w4.w * u3.y;
            acc[ff][2] += w4.x * u0.z + w4.y * u1.z + w4.z * u2.z + w4.w * u3.z;
            acc[ff][3] += w4.x * u0.w + w4.y * u1.w + w4.z * u2.w + w4.w * u3.w;
        }
    }
    float po[4] = {};
    #pragma unroll
    for (int ff = 0; ff < 8; ++ff) {
        int f = fg * 8 + ff;
        float bb = b1[f], w2v = w2[f];
        #pragma unroll
        for (int xi = 0; xi < 4; ++xi) po[xi] += w2v * gelu_f(acc[ff][xi] + bb);
    }
    #pragma unroll
    for (int xi = 0; xi < 4; ++xi) red[fg][xg][xi] = po[xi];
    __syncthreads();
    if (tid < 64) {
        int xg2 = tid >> 2, xi = tid & 3;
        float s = b2[0];
        #pragma unroll
        for (int g = 0; g < 16; ++g) s += red[g][xg2][xi];
        out[(size_t)b * N + x0 + xg2 * 4 + xi] = s;
    }
}

extern "C" void kernel_launch(void* const* d_in, const int* in_sizes, int n_in,
                              void* d_out, int out_size, void* d_ws, size_t ws_size,
                              hipStream_t stream) {
    const float* u_in = (const float*)d_in[0];
    const float* v_in = (const float*)d_in[1];
    const float* nodes_u = (const float*)d_in[3];
    const float* nodes_v = (const float*)d_in[4];
    const float* nwu = (const float*)d_in[5];
    const float* nwv = (const float*)d_in[6];
    const float* modes = (const float*)d_in[7];
    const float* latent = (const float*)d_in[8];
    const float* fc0uw = (const float*)d_in[9];
    const float* fc0ub = (const float*)d_in[10];
    const float* fc0vw = (const float*)d_in[11];
    const float* fc0vb = (const float*)d_in[12];
    const float* ewc = (const float*)d_in[13];
    const float* ews = (const float*)d_in[14];
    const float* ew0 = (const float*)d_in[15];
    const float* uwc = (const float*)d_in[16];
    const float* uws = (const float*)d_in[17];
    const float* uw0 = (const float*)d_in[18];
    const float* vwc = (const float*)d_in[19];
    const float* vws = (const float*)d_in[20];
    const float* vw0 = (const float*)d_in[21];
    const float* wsuw = (const float*)d_in[22];
    const float* wsub = (const float*)d_in[23];
    const float* wsvw = (const float*)d_in[24];
    const float* wsvb = (const float*)d_in[25];
    const float* fc1w = (const float*)d_in[26];
    const float* fc1b = (const float*)d_in[27];
    const float* fc2w = (const float*)d_in[28];
    const float* fc2b = (const float*)d_in[29];
    float* out = (float*)d_out;

    const int B = 4, NU = 65536, NV = 16384;
    float* ws = (float*)d_ws;
    float* bases_u = ws;
    float* bases_v = bases_u + (size_t)B * 64 * NU;
    float* ubuf = bases_v + (size_t)B * 64 * NV;
    float* vbuf = ubuf + (size_t)B * 64 * NU;
    float* partial = vbuf + (size_t)B * 64 * NV;
    float* momu = partial + (size_t)B * 64 * 64 * 66;
    float* momv = momu + B * 64 * 66;
    float* Wu = momv + B * 64 * 66;
    float* Wv = Wu + B * 64 * 132;
    float* wT = Wv + B * 64 * 132;
    size_t need_T = ((size_t)(wT - ws) + 6u * 393216u) * sizeof(float);
    int use_T = (ws_size >= need_T) ? 1 : 0;

    k_bases<<<dim3(NU / 256, B), 256, 0, stream>>>(nodes_u, modes, latent, bases_u, NU);
    k_bases<<<dim3(NV / 256, B), 256, 0, stream>>>(nodes_v, modes, latent, bases_v, NV);
    k_fc0<<<dim3(NU / 256, B), 256, 0, stream>>>(u_in, fc0uw, fc0ub, ubuf, NU, 2);
    k_fc0<<<dim3(NV / 256, B), 256, 0, stream>>>(v_in, fc0vw, fc0vb, vbuf, NV, 3);
    if (use_T)
        k_tw<<<dim3(192, 6), 256, 0, stream>>>(ewc, ews, uwc, uws, vwc, vws, wT);

    for (int l = 0; l < 3; ++l) {
        int do_v = (l < 2) ? 1 : 0;
        k_analysis<<<dim3(64, B), 256, 0, stream>>>(ubuf, nwu, bases_u, partial, NU, 64);
        k_reduce<<<dim3(17, B), 256, 0, stream>>>(partial, momu, 64);
        k_analysis<<<dim3(64, B), 256, 0, stream>>>(vbuf, nwv, bases_v, partial, NV, 64);
        k_reduce<<<dim3(17, B), 256, 0, stream>>>(partial, momv, 64);
        if (use_T) {
            k_buildW<<<dim3(33, B), 64, 0, stream>>>(momu, momv,
                wT + 0 * 393216 + l * 131072, wT + 1 * 393216 + l * 131072, ew0 + (size_t)l * 64 * 64,
                wT + 2 * 393216 + l * 131072, wT + 3 * 393216 + l * 131072, uw0 + (size_t)l * 64 * 64,
                wT + 4 * 393216 + l * 131072, wT + 5 * 393216 + l * 131072, vw0 + (size_t)l * 64 * 64,
                wsuw + l * 64 * 64, wsub + l * 64, wsvw + l * 64 * 64, wsvb + l * 64,
                Wu, Wv, do_v);
        } else {
            k_buildW_slow<<<dim3(33, B), 64, 0, stream>>>(momu, momv,
                ewc + (size_t)l * 64 * 64 * 32, ews + (size_t)l * 64 * 64 * 32, ew0 + (size_t)l * 64 * 64,
                uwc + (size_t)l * 64 * 64 * 32, uws + (size_t)l * 64 * 64 * 32, uw0 + (size_t)l * 64 * 64,
                vwc + (size_t)l * 64 * 64 * 32, vws + (size_t)l * 64 * 64 * 32, vw0 + (size_t)l * 64 * 64,
                wsuw + l * 64 * 64, wsub + l * 64, wsvw + l * 64 * 64, wsvb + l * 64,
                Wu, Wv, do_v);
        }
        k_synth<<<dim3(NU / 256, B), 256, 0, stream>>>(Wu, bases_u, ubuf, ubuf, NU, do_v);
        if (do_v)
            k_synth<<<dim3(NV / 256, B), 256, 0, stream>>>(Wv, bases_v, vbuf, vbuf, NV, 1);
    }
    k_fc12<<<dim3(NU / 64, B), 256, 0, stream>>>(ubuf, fc1w, fc1b, fc2w, fc2b, out, NU);
}

// Round 5
// 695.363 us; speedup vs baseline: 3.3527x; 1.3508x over previous
//
#include <hip/hip_runtime.h>
#include <math.h>

#define PI2 6.283185307179586f

typedef __attribute__((ext_vector_type(8))) short bf16x8;
typedef __attribute__((ext_vector_type(4))) float f32x4;

__device__ __forceinline__ float gelu_f(float x) {
    return 0.5f * x * (1.0f + erff(x * 0.7071067811865476f));
}
__device__ __forceinline__ unsigned short f2bf(float f) {
    unsigned int u = __float_as_uint(f);
    u += 0x7FFFu + ((u >> 16) & 1u);
    return (unsigned short)(u >> 16);
}
__device__ __forceinline__ float bf2f(unsigned short h) {
    return __uint_as_float(((unsigned int)h) << 16);
}
__device__ __forceinline__ unsigned int pk(unsigned short a, unsigned short b) {
    return (unsigned int)a | ((unsigned int)b << 16);
}

// ---- bases: FT[b][x][0..63] = [cos;sin] bf16 (unweighted);
//      wbb[b][k][x]: k<32 cos*w, 32..63 sin*w, 64: w  (bf16 planes) ----
__global__ void k_bases(const float* __restrict__ nodes, const float* __restrict__ modes,
                        const float* __restrict__ latent, const float* __restrict__ nw,
                        unsigned short* __restrict__ FT, unsigned short* __restrict__ wbb, int N) {
    int b = blockIdx.y;
    int x = blockIdx.x * 256 + threadIdx.x;
    float s0 = 0.5f + 1.5f / (1.0f + expf(-latent[0]));
    float s1 = 0.5f + 1.5f / (1.0f + expf(-latent[1]));
    float n0 = nodes[((size_t)b * N + x) * 2 + 0];
    float n1 = nodes[((size_t)b * N + x) * 2 + 1];
    float wx = nw[(size_t)b * N + x];
    unsigned short* fr = FT + ((size_t)b * N + x) * 128;
    unsigned short* wb = wbb + (size_t)b * 65 * N + x;
    unsigned int fc[16];
    #pragma unroll
    for (int k = 0; k < 32; ++k) {
        float m0 = modes[k * 2 + 0] * s0;
        float m1 = modes[k * 2 + 1] * s1;
        float t = PI2 * (n0 * m0 + n1 * m1);
        float s, c;
        sincosf(t, &s, &c);
        unsigned short hc = f2bf(c), hs = f2bf(s);
        if (k & 1) { fc[k >> 1] |= ((unsigned int)hc << 16); fc[8 + (k >> 1)] |= ((unsigned int)hs << 16); }
        else       { fc[k >> 1] = hc;                         fc[8 + (k >> 1)] = hs; }
        wb[(size_t)k * N] = f2bf(c * wx);
        wb[(size_t)(32 + k) * N] = f2bf(s * wx);
    }
    wb[(size_t)64 * N] = f2bf(wx);
    #pragma unroll
    for (int i = 0; i < 16; ++i) ((unsigned int*)fr)[i] = fc[i];
}

// ---- fc0: chbf planes [b][c][x] + FT[b][x][64+c] ----
__global__ void k_fc0(const float* __restrict__ in, const float* __restrict__ w,
                      const float* __restrict__ bias, unsigned short* __restrict__ chbf,
                      unsigned short* __restrict__ FT, int N, int nin) {
    int b = blockIdx.y;
    int x = blockIdx.x * 256 + threadIdx.x;
    float xi[3];
    for (int i = 0; i < nin; ++i) xi[i] = in[((size_t)b * N + x) * nin + i];
    unsigned short* cb = chbf + (size_t)b * 64 * N + x;
    unsigned short* fr = FT + ((size_t)b * N + x) * 128 + 64;
    unsigned int fc[32];
    for (int c = 0; c < 64; ++c) {
        float a = bias[c];
        for (int i = 0; i < nin; ++i) a += w[c * nin + i] * xi[i];
        unsigned short h = f2bf(a);
        cb[(size_t)c * N] = h;
        if (c & 1) fc[c >> 1] |= ((unsigned int)h << 16);
        else fc[c >> 1] = h;
    }
    #pragma unroll
    for (int i = 0; i < 32; ++i) ((unsigned int*)fr)[i] = fc[i];
}

// ---- analysis (MFMA): partial[b][chunk][i][col] fp32, col<64 from wbb planes, 64: w-moment ----
__global__ __launch_bounds__(256) void k_analysis(const unsigned short* __restrict__ chbf,
                                                  const unsigned short* __restrict__ wbb,
                                                  float* __restrict__ partial, int N, int nch) {
    int b = blockIdx.y, chunk = blockIdx.x, tid = threadIdx.x;
    int lane = tid & 63, wv = tid >> 6;
    int lm = lane & 15, lg = lane >> 4;
    int ro = wv * 16;
    const unsigned short* chb = chbf + (size_t)b * 64 * N;
    const unsigned short* wb = wbb + (size_t)b * 65 * N;
    int xlen = N / nch, x0 = chunk * xlen;
    f32x4 acc[5] = {};
    for (int x = x0; x < x0 + xlen; x += 32) {
        bf16x8 a = *(const bf16x8*)(chb + (size_t)(ro + lm) * N + x + lg * 8);
        #pragma unroll
        for (int ct = 0; ct < 4; ++ct) {
            bf16x8 bf = *(const bf16x8*)(wb + (size_t)(ct * 16 + lm) * N + x + lg * 8);
            acc[ct] = __builtin_amdgcn_mfma_f32_16x16x32_bf16(a, bf, acc[ct], 0, 0, 0);
        }
        bf16x8 wf = *(const bf16x8*)(wb + (size_t)64 * N + x + lg * 8);
        acc[4] = __builtin_amdgcn_mfma_f32_16x16x32_bf16(a, wf, acc[4], 0, 0, 0);
    }
    float* pb = partial + (size_t)(b * nch + chunk) * 64 * 66;
    #pragma unroll
    for (int ct = 0; ct < 4; ++ct)
        #pragma unroll
        for (int j = 0; j < 4; ++j)
            pb[(ro + lg * 4 + j) * 66 + ct * 16 + lm] = acc[ct][j];
    if (lm == 0) {
        #pragma unroll
        for (int j = 0; j < 4; ++j) pb[(ro + lg * 4 + j) * 66 + 64] = acc[4][j];
    }
}

// ---- reduce partials -> mom[b][i][col] stride 66 ----
__global__ void k_reduce(const float* __restrict__ partial, float* __restrict__ mom, int nch) {
    int b = blockIdx.y;
    int e = blockIdx.x * 256 + threadIdx.x;
    if (e >= 64 * 65) return;
    int row = e / 65, col = e % 65;
    const float* p = partial + ((size_t)(b * nch) * 64 + row) * 66 + col;
    float s = 0.f;
    #pragma unroll 4
    for (int c = 0; c < nch; ++c)
        s += p[(size_t)c * 64 * 66];
    mom[((size_t)b * 64 + row) * 66 + col] = s;
}

// ---- transpose weights (l,i,o,k)->(l,k,i,o) ----
__global__ __launch_bounds__(256) void k_tw(const float* __restrict__ e_c, const float* __restrict__ e_s,
                                            const float* __restrict__ u_c, const float* __restrict__ u_s,
                                            const float* __restrict__ v_c, const float* __restrict__ v_s,
                                            float* __restrict__ oT) {
    int li = blockIdx.x;
    int a = blockIdx.y;
    const float* in;
    switch (a) {
        case 0: in = e_c; break;
        case 1: in = e_s; break;
        case 2: in = u_c; break;
        case 3: in = u_s; break;
        case 4: in = v_c; break;
        default: in = v_s; break;
    }
    float* outp = oT + (size_t)a * 393216;
    int l = li >> 6, i = li & 63;
    __shared__ float t[32][65];
    int tid = threadIdx.x;
    const float* ib = in + (size_t)l * 131072 + (size_t)i * 2048;
    #pragma unroll
    for (int r = 0; r < 8; ++r) {
        int e = r * 256 + tid;
        t[e & 31][e >> 5] = ib[e];
    }
    __syncthreads();
    float* ob = outp + (size_t)l * 131072 + (size_t)i * 64;
    #pragma unroll
    for (int r = 0; r < 8; ++r) {
        int e = r * 256 + tid;
        ob[(size_t)(e >> 6) * 4096 + (e & 63)] = t[e >> 6][e & 63];
    }
}

// ---- buildW (coalesced, transposed weights) -> W[b][o][132] fp32 ----
__global__ void k_buildW(const float* __restrict__ momu, const float* __restrict__ momv,
                         const float* __restrict__ ecT, const float* __restrict__ esT, const float* __restrict__ ew0,
                         const float* __restrict__ ucT, const float* __restrict__ usT, const float* __restrict__ uw0,
                         const float* __restrict__ vcT, const float* __restrict__ vsT, const float* __restrict__ vw0,
                         const float* __restrict__ wsuw, const float* __restrict__ wsub,
                         const float* __restrict__ wsvw, const float* __restrict__ wsvb,
                         float* __restrict__ Wu, float* __restrict__ Wv, int do_v) {
    int b = blockIdx.y, j = blockIdx.x, o = threadIdx.x;
    const float* mu = momu + (size_t)b * 64 * 66;
    const float* mv = momv + (size_t)b * 64 * 66;
    float* Wub = Wu + (size_t)b * 64 * 132;
    float* Wvb = Wv + (size_t)b * 64 * 132;
    if (j < 32) {
        int k = j;
        const float* ec = ecT + (size_t)k * 4096;
        const float* es = esT + (size_t)k * 4096;
        const float* uc = ucT + (size_t)k * 4096;
        const float* us = usT + (size_t)k * 4096;
        const float* vc = vcT + (size_t)k * 4096;
        const float* vs = vsT + (size_t)k * 4096;
        float fcu = 0, fsu = 0, fcv = 0, fsv = 0;
        for (int i = 0; i < 64; ++i) {
            float Scv = mv[i * 66 + k], Ssv = mv[i * 66 + 32 + k];
            float Scu = mu[i * 66 + k], Ssu = mu[i * 66 + 32 + k];
            int wi = i * 64 + o;
            float e_c = ec[wi], e_s = es[wi];
            float u_c = uc[wi], u_s = us[wi];
            fcu += Scv * e_c + Ssv * e_s + Scu * u_c + Ssu * u_s;
            fsu += Scv * e_s - Ssv * e_c + Scu * u_s - Ssu * u_c;
            if (do_v) {
                float v_c = vc[wi], v_s = vs[wi];
                fcv += Scv * v_c + Ssv * v_s;
                fsv += Scv * v_s - Ssv * v_c;
            }
        }
        Wub[o * 132 + k] = 2.f * fcu;
        Wub[o * 132 + 32 + k] = -2.f * fsu;
        if (do_v) {
            Wvb[o * 132 + k] = 2.f * fcv;
            Wvb[o * 132 + 32 + k] = -2.f * fsv;
        }
    } else {
        for (int c = 0; c < 64; ++c) Wub[o * 132 + 64 + c] = wsuw[o * 64 + c];
        float f0u = 0;
        for (int i = 0; i < 64; ++i)
            f0u += mv[i * 66 + 64] * ew0[i * 64 + o] + mu[i * 66 + 64] * uw0[i * 64 + o];
        Wub[o * 132 + 128] = f0u + wsub[o];
        if (do_v) {
            for (int c = 0; c < 64; ++c) Wvb[o * 132 + 64 + c] = wsvw[o * 64 + c];
            float f0v = 0;
            for (int i = 0; i < 64; ++i) f0v += mv[i * 66 + 64] * vw0[i * 64 + o];
            Wvb[o * 132 + 128] = f0v + wsvb[o];
        }
    }
}

// ---- fallback buildW (original layout) ----
__global__ void k_buildW_slow(const float* __restrict__ momu, const float* __restrict__ momv,
                              const float* __restrict__ ewc, const float* __restrict__ ews, const float* __restrict__ ew0,
                              const float* __restrict__ uwc, const float* __restrict__ uws, const float* __restrict__ uw0,
                              const float* __restrict__ vwc, const float* __restrict__ vws, const float* __restrict__ vw0,
                              const float* __restrict__ wsuw, const float* __restrict__ wsub,
                              const float* __restrict__ wsvw, const float* __restrict__ wsvb,
                              float* __restrict__ Wu, float* __restrict__ Wv, int do_v) {
    int b = blockIdx.y, j = blockIdx.x, o = threadIdx.x;
    const float* mu = momu + (size_t)b * 64 * 66;
    const float* mv = momv + (size_t)b * 64 * 66;
    float* Wub = Wu + (size_t)b * 64 * 132;
    float* Wvb = Wv + (size_t)b * 64 * 132;
    if (j < 32) {
        int k = j;
        float fcu = 0, fsu = 0, fcv = 0, fsv = 0;
        for (int i = 0; i < 64; ++i) {
            float Scv = mv[i * 66 + k], Ssv = mv[i * 66 + 32 + k];
            float Scu = mu[i * 66 + k], Ssu = mu[i * 66 + 32 + k];
            int wi = (i * 64 + o) * 32 + k;
            float ec = ewc[wi], es = ews[wi];
            float uc = uwc[wi], us = uws[wi];
            fcu += Scv * ec + Ssv * es + Scu * uc + Ssu * us;
            fsu += Scv * es - Ssv * ec + Scu * us - Ssu * uc;
            if (do_v) {
                float vc = vwc[wi], vs = vws[wi];
                fcv += Scv * vc + Ssv * vs;
                fsv += Scv * vs - Ssv * vc;
            }
        }
        Wub[o * 132 + k] = 2.f * fcu;
        Wub[o * 132 + 32 + k] = -2.f * fsu;
        if (do_v) {
            Wvb[o * 132 + k] = 2.f * fcv;
            Wvb[o * 132 + 32 + k] = -2.f * fsv;
        }
    } else {
        for (int c = 0; c < 64; ++c) Wub[o * 132 + 64 + c] = wsuw[o * 64 + c];
        float f0u = 0;
        for (int i = 0; i < 64; ++i)
            f0u += mv[i * 66 + 64] * ew0[i * 64 + o] + mu[i * 66 + 64] * uw0[i * 64 + o];
        Wub[o * 132 + 128] = f0u + wsub[o];
        if (do_v) {
            for (int c = 0; c < 64; ++c) Wvb[o * 132 + 64 + c] = wsvw[o * 64 + c];
            float f0v = 0;
            for (int i = 0; i < 64; ++i) f0v += mv[i * 66 + 64] * vw0[i * 64 + o];
            Wvb[o * 132 + 128] = f0v + wsvb[o];
        }
    }
}

// ---- synthesis (MFMA): out = act(W(64x128,split-bf16) . FT[x][128] + bias)
// writes chbf planes (+ optionally FT ch cols, in-place after barrier) ----
__global__ __launch_bounds__(256) void k_synth(const float* __restrict__ W, unsigned short* FT,
                                               unsigned short* __restrict__ chbf, int N, int act, int wft) {
    int b = blockIdx.y, blk = blockIdx.x, tid = threadIdx.x;
    int lane = tid & 63, wv = tid >> 6;
    int lm = lane & 15, lg = lane >> 4;
    __shared__ float Wl[64][132];
    for (int idx = tid; idx < 64 * 132; idx += 256) {
        int row = idx / 132, col = idx % 132;
        if (col < 129) Wl[row][col] = W[((size_t)b * 64 + row) * 132 + col];
    }
    __syncthreads();
    bf16x8 ahi[4], alo[4];
    #pragma unroll
    for (int kt = 0; kt < 4; ++kt) {
        float tmp[8];
        *(float4*)&tmp[0] = *(float4*)&Wl[16 * wv + lm][kt * 32 + lg * 8];
        *(float4*)&tmp[4] = *(float4*)&Wl[16 * wv + lm][kt * 32 + lg * 8 + 4];
        #pragma unroll
        for (int i = 0; i < 8; ++i) {
            unsigned short h = f2bf(tmp[i]);
            ahi[kt][i] = (short)h;
            alo[kt][i] = (short)f2bf(tmp[i] - bf2f(h));
        }
    }
    float bias[4];
    #pragma unroll
    for (int j = 0; j < 4; ++j) bias[j] = Wl[16 * wv + lg * 4 + j][128];
    f32x4 acc[8] = {};
    unsigned short* ftb = FT + (size_t)b * N * 128;
    int x0 = blk * 128;
    #pragma unroll
    for (int xt = 0; xt < 8; ++xt) {
        int x = x0 + xt * 16 + lm;
        const unsigned short* fp = ftb + (size_t)x * 128 + lg * 8;
        #pragma unroll
        for (int kt = 0; kt < 4; ++kt) {
            bf16x8 bf = *(const bf16x8*)(fp + kt * 32);
            acc[xt] = __builtin_amdgcn_mfma_f32_16x16x32_bf16(ahi[kt], bf, acc[xt], 0, 0, 0);
            acc[xt] = __builtin_amdgcn_mfma_f32_16x16x32_bf16(alo[kt], bf, acc[xt], 0, 0, 0);
        }
    }
    // all FT reads (all waves) complete before ch-cols are overwritten
    __syncthreads();
    unsigned short* cb = chbf + (size_t)b * 64 * N;
    int r0 = 16 * wv + lg * 4;
    #pragma unroll
    for (int xt = 0; xt < 8; ++xt) {
        int x = x0 + xt * 16 + lm;
        float v[4];
        #pragma unroll
        for (int j = 0; j < 4; ++j) {
            v[j] = acc[xt][j] + bias[j];
            if (act) v[j] = gelu_f(v[j]);
        }
        unsigned short h[4];
        #pragma unroll
        for (int j = 0; j < 4; ++j) {
            h[j] = f2bf(v[j]);
            cb[(size_t)(r0 + j) * N + x] = h[j];
        }
        if (wft) {
            unsigned int* dst = (unsigned int*)(ftb + (size_t)x * 128 + 64 + r0);
            dst[0] = pk(h[0], h[1]);
            dst[1] = pk(h[2], h[3]);
        }
    }
}

// ---- fc1(gelu)+fc2 fused; u read as bf16 planes ----
__global__ __launch_bounds__(256) void k_fc12(const unsigned short* __restrict__ u, const float* __restrict__ w1,
                                              const float* __restrict__ b1, const float* __restrict__ w2,
                                              const float* __restrict__ b2, float* __restrict__ out, int N) {
    int b = blockIdx.y, blk = blockIdx.x, tid = threadIdx.x;
    __shared__ float w1s[128][64];
    __shared__ float us[64][64];
    __shared__ float red[16][16][4];
    for (int e = tid; e < 2048; e += 256)
        ((float4*)&w1s[0][0])[e] = ((const float4*)w1)[e];
    const unsigned short* ub = u + (size_t)b * 64 * N;
    int x0 = blk * 64;
    #pragma unroll
    for (int r = 0; r < 4; ++r) {
        int idx = r * 256 + tid;
        int c = idx >> 4, q = idx & 15;
        const unsigned short* p = ub + (size_t)c * N + x0 + q * 4;
        us[c][q * 4 + 0] = bf2f(p[0]);
        us[c][q * 4 + 1] = bf2f(p[1]);
        us[c][q * 4 + 2] = bf2f(p[2]);
        us[c][q * 4 + 3] = bf2f(p[3]);
    }
    __syncthreads();
    int fg = tid >> 4, xg = tid & 15;
    float acc[8][4] = {};
    for (int c = 0; c < 64; c += 4) {
        float4 u0 = *(float4*)&us[c + 0][xg * 4];
        float4 u1 = *(float4*)&us[c + 1][xg * 4];
        float4 u2 = *(float4*)&us[c + 2][xg * 4];
        float4 u3 = *(float4*)&us[c + 3][xg * 4];
        #pragma unroll
        for (int ff = 0; ff < 8; ++ff) {
            float4 w4 = *(float4*)&w1s[fg * 8 + ff][c];
            acc[ff][0] += w4.x * u0.x + w4.y * u1.x + w4.z * u2.x + w4.w * u3.x;
            acc[ff][1] += w4.x * u0.y + w4.y * u1.y + w4.z * u2.y + w4.w * u3.y;
            acc[ff][2] += w4.x * u0.z + w4.y * u1.z + w4.z * u2.z + w4.w * u3.z;
            acc[ff][3] += w4.x * u0.w + w4.y * u1.w + w4.z * u2.w + w4.w * u3.w;
        }
    }
    float po[4] = {};
    #pragma unroll
    for (int ff = 0; ff < 8; ++ff) {
        int f = fg * 8 + ff;
        float bb = b1[f], w2v = w2[f];
        #pragma unroll
        for (int xi = 0; xi < 4; ++xi) po[xi] += w2v * gelu_f(acc[ff][xi] + bb);
    }
    #pragma unroll
    for (int xi = 0; xi < 4; ++xi) red[fg][xg][xi] = po[xi];
    __syncthreads();
    if (tid < 64) {
        int xg2 = tid >> 2, xi = tid & 3;
        float s = b2[0];
        #pragma unroll
        for (int g = 0; g < 16; ++g) s += red[g][xg2][xi];
        out[(size_t)b * N + x0 + xg2 * 4 + xi] = s;
    }
}

extern "C" void kernel_launch(void* const* d_in, const int* in_sizes, int n_in,
                              void* d_out, int out_size, void* d_ws, size_t ws_size,
                              hipStream_t stream) {
    const float* u_in = (const float*)d_in[0];
    const float* v_in = (const float*)d_in[1];
    const float* nodes_u = (const float*)d_in[3];
    const float* nodes_v = (const float*)d_in[4];
    const float* nwu = (const float*)d_in[5];
    const float* nwv = (const float*)d_in[6];
    const float* modes = (const float*)d_in[7];
    const float* latent = (const float*)d_in[8];
    const float* fc0uw = (const float*)d_in[9];
    const float* fc0ub = (const float*)d_in[10];
    const float* fc0vw = (const float*)d_in[11];
    const float* fc0vb = (const float*)d_in[12];
    const float* ewc = (const float*)d_in[13];
    const float* ews = (const float*)d_in[14];
    const float* ew0 = (const float*)d_in[15];
    const float* uwc = (const float*)d_in[16];
    const float* uws = (const float*)d_in[17];
    const float* uw0 = (const float*)d_in[18];
    const float* vwc = (const float*)d_in[19];
    const float* vws = (const float*)d_in[20];
    const float* vw0 = (const float*)d_in[21];
    const float* wsuw = (const float*)d_in[22];
    const float* wsub = (const float*)d_in[23];
    const float* wsvw = (const float*)d_in[24];
    const float* wsvb = (const float*)d_in[25];
    const float* fc1w = (const float*)d_in[26];
    const float* fc1b = (const float*)d_in[27];
    const float* fc2w = (const float*)d_in[28];
    const float* fc2b = (const float*)d_in[29];
    float* out = (float*)d_out;

    const int B = 4, NU = 65536, NV = 16384;
    const int CH_U = 256, CH_V = 128;  // analysis split-K chunks

    unsigned short* FT_u = (unsigned short*)d_ws;
    unsigned short* FT_v = FT_u + (size_t)B * NU * 128;
    unsigned short* wbb_u = FT_v + (size_t)B * NV * 128;
    unsigned short* wbb_v = wbb_u + (size_t)B * 65 * NU;
    unsigned short* chbf_u = wbb_v + (size_t)B * 65 * NV;
    unsigned short* chbf_v = chbf_u + (size_t)B * 64 * NU;
    float* partial = (float*)(chbf_v + (size_t)B * 64 * NV);
    float* momu = partial + (size_t)B * CH_U * 64 * 66;
    float* momv = momu + B * 64 * 66;
    float* Wu = momv + B * 64 * 66;
    float* Wv = Wu + B * 64 * 132;
    float* wT = Wv + B * 64 * 132;
    size_t need_T = (size_t)((char*)(wT + 6 * 393216) - (char*)d_ws);
    int use_T = (ws_size >= need_T) ? 1 : 0;

    k_bases<<<dim3(NU / 256, B), 256, 0, stream>>>(nodes_u, modes, latent, nwu, FT_u, wbb_u, NU);
    k_bases<<<dim3(NV / 256, B), 256, 0, stream>>>(nodes_v, modes, latent, nwv, FT_v, wbb_v, NV);
    k_fc0<<<dim3(NU / 256, B), 256, 0, stream>>>(u_in, fc0uw, fc0ub, chbf_u, FT_u, NU, 2);
    k_fc0<<<dim3(NV / 256, B), 256, 0, stream>>>(v_in, fc0vw, fc0vb, chbf_v, FT_v, NV, 3);
    if (use_T)
        k_tw<<<dim3(192, 6), 256, 0, stream>>>(ewc, ews, uwc, uws, vwc, vws, wT);

    for (int l = 0; l < 3; ++l) {
        int do_v = (l < 2) ? 1 : 0;
        k_analysis<<<dim3(CH_U, B), 256, 0, stream>>>(chbf_u, wbb_u, partial, NU, CH_U);
        k_reduce<<<dim3(17, B), 256, 0, stream>>>(partial, momu, CH_U);
        k_analysis<<<dim3(CH_V, B), 256, 0, stream>>>(chbf_v, wbb_v, partial, NV, CH_V);
        k_reduce<<<dim3(17, B), 256, 0, stream>>>(partial, momv, CH_V);
        if (use_T) {
            k_buildW<<<dim3(33, B), 64, 0, stream>>>(momu, momv,
                wT + 0 * 393216 + l * 131072, wT + 1 * 393216 + l * 131072, ew0 + (size_t)l * 64 * 64,
                wT + 2 * 393216 + l * 131072, wT + 3 * 393216 + l * 131072, uw0 + (size_t)l * 64 * 64,
                wT + 4 * 393216 + l * 131072, wT + 5 * 393216 + l * 131072, vw0 + (size_t)l * 64 * 64,
                wsuw + l * 64 * 64, wsub + l * 64, wsvw + l * 64 * 64, wsvb + l * 64,
                Wu, Wv, do_v);
        } else {
            k_buildW_slow<<<dim3(33, B), 64, 0, stream>>>(momu, momv,
                ewc + (size_t)l * 64 * 64 * 32, ews + (size_t)l * 64 * 64 * 32, ew0 + (size_t)l * 64 * 64,
                uwc + (size_t)l * 64 * 64 * 32, uws + (size_t)l * 64 * 64 * 32, uw0 + (size_t)l * 64 * 64,
                vwc + (size_t)l * 64 * 64 * 32, vws + (size_t)l * 64 * 64 * 32, vw0 + (size_t)l * 64 * 64,
                wsuw + l * 64 * 64, wsub + l * 64, wsvw + l * 64 * 64, wsvb + l * 64,
                Wu, Wv, do_v);
        }
        k_synth<<<dim3(NU / 128, B), 256, 0, stream>>>(Wu, FT_u, chbf_u, NU, do_v, do_v);
        if (do_v)
            k_synth<<<dim3(NV / 128, B), 256, 0, stream>>>(Wv, FT_v, chbf_v, NV, 1, 1);
    }
    k_fc12<<<dim3(NU / 64, B), 256, 0, stream>>>(chbf_u, fc1w, fc1b, fc2w, fc2b, out, NU);
}

// Round 6
// 694.718 us; speedup vs baseline: 3.3558x; 1.0009x over previous
//
#include <hip/hip_runtime.h>
#include <math.h>

#define PI2 6.283185307179586f

typedef __attribute__((ext_vector_type(8))) short bf16x8;
typedef __attribute__((ext_vector_type(4))) float f32x4;

__device__ __forceinline__ float gelu_f(float x) {
    return 0.5f * x * (1.0f + erff(x * 0.7071067811865476f));
}
__device__ __forceinline__ unsigned short f2bf(float f) {
    unsigned int u = __float_as_uint(f);
    u += 0x7FFFu + ((u >> 16) & 1u);
    return (unsigned short)(u >> 16);
}
__device__ __forceinline__ float bf2f(unsigned short h) {
    return __uint_as_float(((unsigned int)h) << 16);
}
__device__ __forceinline__ unsigned int pk(unsigned short a, unsigned short b) {
    return (unsigned int)a | ((unsigned int)b << 16);
}

// ---- fused bases + fc0: FT[b][x][128] = [cos32; sin32; ch64] bf16 (one 256B store),
//      wbb planes [b][k][x] (k<32 cos*w, 32..63 sin*w, 64 w), chbf planes [b][c][x] ----
__global__ __launch_bounds__(256) void k_prep(const float* __restrict__ nodes, const float* __restrict__ modes,
                                              const float* __restrict__ latent, const float* __restrict__ nw,
                                              const float* __restrict__ inp, const float* __restrict__ fcw,
                                              const float* __restrict__ fcb,
                                              unsigned short* __restrict__ FT, unsigned short* __restrict__ wbb,
                                              unsigned short* __restrict__ chbf, int N, int nin) {
    int b = blockIdx.y;
    int x = blockIdx.x * 256 + threadIdx.x;
    float s0 = 0.5f + 1.5f / (1.0f + expf(-latent[0]));
    float s1 = 0.5f + 1.5f / (1.0f + expf(-latent[1]));
    float n0 = nodes[((size_t)b * N + x) * 2 + 0];
    float n1 = nodes[((size_t)b * N + x) * 2 + 1];
    float wx = nw[(size_t)b * N + x];
    unsigned short* wb = wbb + (size_t)b * 65 * N + x;
    unsigned int row[64];
    #pragma unroll
    for (int k = 0; k < 32; ++k) {
        float m0 = modes[k * 2 + 0] * s0;
        float m1 = modes[k * 2 + 1] * s1;
        float t = PI2 * (n0 * m0 + n1 * m1);
        float s, c;
        sincosf(t, &s, &c);
        unsigned short hc = f2bf(c), hs = f2bf(s);
        if (k & 1) { row[k >> 1] |= ((unsigned int)hc << 16); row[16 + (k >> 1)] |= ((unsigned int)hs << 16); }
        else       { row[k >> 1] = hc;                         row[16 + (k >> 1)] = hs; }
        wb[(size_t)k * N] = f2bf(c * wx);
        wb[(size_t)(32 + k) * N] = f2bf(s * wx);
    }
    wb[(size_t)64 * N] = f2bf(wx);
    // fc0
    float xi[3];
    for (int i = 0; i < nin; ++i) xi[i] = inp[((size_t)b * N + x) * nin + i];
    unsigned short* cb = chbf + (size_t)b * 64 * N + x;
    for (int c = 0; c < 64; ++c) {
        float a = fcb[c];
        for (int i = 0; i < nin; ++i) a += fcw[c * nin + i] * xi[i];
        unsigned short h = f2bf(a);
        cb[(size_t)c * N] = h;
        if (c & 1) row[32 + (c >> 1)] |= ((unsigned int)h << 16);
        else row[32 + (c >> 1)] = h;
    }
    unsigned int* fr = (unsigned int*)(FT + ((size_t)b * N + x) * 128);
    #pragma unroll
    for (int i = 0; i < 64; ++i) fr[i] = row[i];
}

// ---- fused analysis u+v (MFMA): partial[b][chunk][i][col] fp32 ----
__global__ __launch_bounds__(256) void k_analysis2(const unsigned short* __restrict__ chbf_u,
                                                   const unsigned short* __restrict__ wbb_u,
                                                   const unsigned short* __restrict__ chbf_v,
                                                   const unsigned short* __restrict__ wbb_v,
                                                   float* __restrict__ part_u, float* __restrict__ part_v,
                                                   int NU_, int NV_, int chu, int chv) {
    int b = blockIdx.y, bx = blockIdx.x, tid = threadIdx.x;
    const unsigned short *chb, *wb;
    float* pb;
    int N, xlen, chunk;
    if (bx < chu) {
        chunk = bx; N = NU_; xlen = NU_ / chu;
        chb = chbf_u + (size_t)b * 64 * N;
        wb = wbb_u + (size_t)b * 65 * N;
        pb = part_u + (size_t)(b * chu + chunk) * 64 * 66;
    } else {
        chunk = bx - chu; N = NV_; xlen = NV_ / chv;
        chb = chbf_v + (size_t)b * 64 * N;
        wb = wbb_v + (size_t)b * 65 * N;
        pb = part_v + (size_t)(b * chv + chunk) * 64 * 66;
    }
    int lane = tid & 63, wv = tid >> 6;
    int lm = lane & 15, lg = lane >> 4;
    int ro = wv * 16;
    int x0 = chunk * xlen;
    f32x4 acc[5] = {};
    for (int x = x0; x < x0 + xlen; x += 32) {
        bf16x8 a = *(const bf16x8*)(chb + (size_t)(ro + lm) * N + x + lg * 8);
        #pragma unroll
        for (int ct = 0; ct < 4; ++ct) {
            bf16x8 bf = *(const bf16x8*)(wb + (size_t)(ct * 16 + lm) * N + x + lg * 8);
            acc[ct] = __builtin_amdgcn_mfma_f32_16x16x32_bf16(a, bf, acc[ct], 0, 0, 0);
        }
        bf16x8 wf = *(const bf16x8*)(wb + (size_t)64 * N + x + lg * 8);
        acc[4] = __builtin_amdgcn_mfma_f32_16x16x32_bf16(a, wf, acc[4], 0, 0, 0);
    }
    #pragma unroll
    for (int ct = 0; ct < 4; ++ct)
        #pragma unroll
        for (int j = 0; j < 4; ++j)
            pb[(ro + lg * 4 + j) * 66 + ct * 16 + lm] = acc[ct][j];
    if (lm == 0) {
        #pragma unroll
        for (int j = 0; j < 4; ++j) pb[(ro + lg * 4 + j) * 66 + 64] = acc[4][j];
    }
}

// ---- fused reduce u+v -> mom[b][i][col] stride 66 ----
__global__ void k_reduce2(const float* __restrict__ part_u, const float* __restrict__ part_v,
                          float* __restrict__ momu, float* __restrict__ momv, int chu, int chv, int B_) {
    int by = blockIdx.y;
    const float* p;
    float* m;
    int nch, b;
    if (by < B_) { b = by; p = part_u; m = momu; nch = chu; }
    else { b = by - B_; p = part_v; m = momv; nch = chv; }
    int e = blockIdx.x * 256 + threadIdx.x;
    if (e >= 64 * 65) return;
    int row = e / 65, col = e % 65;
    const float* pp = p + ((size_t)(b * nch) * 64 + row) * 66 + col;
    float s = 0.f;
    #pragma unroll 4
    for (int c = 0; c < nch; ++c)
        s += pp[(size_t)c * 64 * 66];
    m[((size_t)b * 64 + row) * 66 + col] = s;
}

// ---- transpose weights (l,i,o,k)->(l,k,i,o) ----
__global__ __launch_bounds__(256) void k_tw(const float* __restrict__ e_c, const float* __restrict__ e_s,
                                            const float* __restrict__ u_c, const float* __restrict__ u_s,
                                            const float* __restrict__ v_c, const float* __restrict__ v_s,
                                            float* __restrict__ oT) {
    int li = blockIdx.x;
    int a = blockIdx.y;
    const float* in;
    switch (a) {
        case 0: in = e_c; break;
        case 1: in = e_s; break;
        case 2: in = u_c; break;
        case 3: in = u_s; break;
        case 4: in = v_c; break;
        default: in = v_s; break;
    }
    float* outp = oT + (size_t)a * 393216;
    int l = li >> 6, i = li & 63;
    __shared__ float t[32][65];
    int tid = threadIdx.x;
    const float* ib = in + (size_t)l * 131072 + (size_t)i * 2048;
    #pragma unroll
    for (int r = 0; r < 8; ++r) {
        int e = r * 256 + tid;
        t[e & 31][e >> 5] = ib[e];
    }
    __syncthreads();
    float* ob = outp + (size_t)l * 131072 + (size_t)i * 64;
    #pragma unroll
    for (int r = 0; r < 8; ++r) {
        int e = r * 256 + tid;
        ob[(size_t)(e >> 6) * 4096 + (e & 63)] = t[e >> 6][e & 63];
    }
}

// ---- buildW (coalesced, transposed weights) -> W[b][o][132] fp32 ----
__global__ void k_buildW(const float* __restrict__ momu, const float* __restrict__ momv,
                         const float* __restrict__ ecT, const float* __restrict__ esT, const float* __restrict__ ew0,
                         const float* __restrict__ ucT, const float* __restrict__ usT, const float* __restrict__ uw0,
                         const float* __restrict__ vcT, const float* __restrict__ vsT, const float* __restrict__ vw0,
                         const float* __restrict__ wsuw, const float* __restrict__ wsub,
                         const float* __restrict__ wsvw, const float* __restrict__ wsvb,
                         float* __restrict__ Wu, float* __restrict__ Wv, int do_v) {
    int b = blockIdx.y, j = blockIdx.x, o = threadIdx.x;
    const float* mu = momu + (size_t)b * 64 * 66;
    const float* mv = momv + (size_t)b * 64 * 66;
    float* Wub = Wu + (size_t)b * 64 * 132;
    float* Wvb = Wv + (size_t)b * 64 * 132;
    if (j < 32) {
        int k = j;
        const float* ec = ecT + (size_t)k * 4096;
        const float* es = esT + (size_t)k * 4096;
        const float* uc = ucT + (size_t)k * 4096;
        const float* us = usT + (size_t)k * 4096;
        const float* vc = vcT + (size_t)k * 4096;
        const float* vs = vsT + (size_t)k * 4096;
        float fcu = 0, fsu = 0, fcv = 0, fsv = 0;
        for (int i = 0; i < 64; ++i) {
            float Scv = mv[i * 66 + k], Ssv = mv[i * 66 + 32 + k];
            float Scu = mu[i * 66 + k], Ssu = mu[i * 66 + 32 + k];
            int wi = i * 64 + o;
            float e_c = ec[wi], e_s = es[wi];
            float u_c = uc[wi], u_s = us[wi];
            fcu += Scv * e_c + Ssv * e_s + Scu * u_c + Ssu * u_s;
            fsu += Scv * e_s - Ssv * e_c + Scu * u_s - Ssu * u_c;
            if (do_v) {
                float v_c = vc[wi], v_s = vs[wi];
                fcv += Scv * v_c + Ssv * v_s;
                fsv += Scv * v_s - Ssv * v_c;
            }
        }
        Wub[o * 132 + k] = 2.f * fcu;
        Wub[o * 132 + 32 + k] = -2.f * fsu;
        if (do_v) {
            Wvb[o * 132 + k] = 2.f * fcv;
            Wvb[o * 132 + 32 + k] = -2.f * fsv;
        }
    } else {
        for (int c = 0; c < 64; ++c) Wub[o * 132 + 64 + c] = wsuw[o * 64 + c];
        float f0u = 0;
        for (int i = 0; i < 64; ++i)
            f0u += mv[i * 66 + 64] * ew0[i * 64 + o] + mu[i * 66 + 64] * uw0[i * 64 + o];
        Wub[o * 132 + 128] = f0u + wsub[o];
        if (do_v) {
            for (int c = 0; c < 64; ++c) Wvb[o * 132 + 64 + c] = wsvw[o * 64 + c];
            float f0v = 0;
            for (int i = 0; i < 64; ++i) f0v += mv[i * 66 + 64] * vw0[i * 64 + o];
            Wvb[o * 132 + 128] = f0v + wsvb[o];
        }
    }
}

// ---- fallback buildW (original layout) ----
__global__ void k_buildW_slow(const float* __restrict__ momu, const float* __restrict__ momv,
                              const float* __restrict__ ewc, const float* __restrict__ ews, const float* __restrict__ ew0,
                              const float* __restrict__ uwc, const float* __restrict__ uws, const float* __restrict__ uw0,
                              const float* __restrict__ vwc, const float* __restrict__ vws, const float* __restrict__ vw0,
                              const float* __restrict__ wsuw, const float* __restrict__ wsub,
                              const float* __restrict__ wsvw, const float* __restrict__ wsvb,
                              float* __restrict__ Wu, float* __restrict__ Wv, int do_v) {
    int b = blockIdx.y, j = blockIdx.x, o = threadIdx.x;
    const float* mu = momu + (size_t)b * 64 * 66;
    const float* mv = momv + (size_t)b * 64 * 66;
    float* Wub = Wu + (size_t)b * 64 * 132;
    float* Wvb = Wv + (size_t)b * 64 * 132;
    if (j < 32) {
        int k = j;
        float fcu = 0, fsu = 0, fcv = 0, fsv = 0;
        for (int i = 0; i < 64; ++i) {
            float Scv = mv[i * 66 + k], Ssv = mv[i * 66 + 32 + k];
            float Scu = mu[i * 66 + k], Ssu = mu[i * 66 + 32 + k];
            int wi = (i * 64 + o) * 32 + k;
            float ec = ewc[wi], es = ews[wi];
            float uc = uwc[wi], us = uws[wi];
            fcu += Scv * ec + Ssv * es + Scu * uc + Ssu * us;
            fsu += Scv * es - Ssv * ec + Scu * us - Ssu * uc;
            if (do_v) {
                float vc = vwc[wi], vs = vws[wi];
                fcv += Scv * vc + Ssv * vs;
                fsv += Scv * vs - Ssv * vc;
            }
        }
        Wub[o * 132 + k] = 2.f * fcu;
        Wub[o * 132 + 32 + k] = -2.f * fsu;
        if (do_v) {
            Wvb[o * 132 + k] = 2.f * fcv;
            Wvb[o * 132 + 32 + k] = -2.f * fsv;
        }
    } else {
        for (int c = 0; c < 64; ++c) Wub[o * 132 + 64 + c] = wsuw[o * 64 + c];
        float f0u = 0;
        for (int i = 0; i < 64; ++i)
            f0u += mv[i * 66 + 64] * ew0[i * 64 + o] + mu[i * 66 + 64] * uw0[i * 64 + o];
        Wub[o * 132 + 128] = f0u + wsub[o];
        if (do_v) {
            for (int c = 0; c < 64; ++c) Wvb[o * 132 + 64 + c] = wsvw[o * 64 + c];
            float f0v = 0;
            for (int i = 0; i < 64; ++i) f0v += mv[i * 66 + 64] * vw0[i * 64 + o];
            Wvb[o * 132 + 128] = f0v + wsvb[o];
        }
    }
}

// ---- fused synthesis u+v (MFMA): out = act(W(64x128,split-bf16) . FT[x][128] + bias) ----
__global__ __launch_bounds__(256) void k_synth2(const float* __restrict__ Wu, const float* __restrict__ Wv,
                                                unsigned short* FTu, unsigned short* FTv,
                                                unsigned short* __restrict__ cbu, unsigned short* __restrict__ cbv,
                                                int NU_, int NV_, int nbu, int act_u, int wch_u) {
    int bx = blockIdx.x, b = blockIdx.y, tid = threadIdx.x;
    const float* W;
    unsigned short *FT, *cbp;
    int N, act, wch, blk;
    if (bx < nbu) { W = Wu; FT = FTu; cbp = cbu; N = NU_; act = act_u; wch = wch_u; blk = bx; }
    else { W = Wv; FT = FTv; cbp = cbv; N = NV_; act = 1; wch = 1; blk = bx - nbu; }
    int lane = tid & 63, wv = tid >> 6;
    int lm = lane & 15, lg = lane >> 4;
    __shared__ float Wl[64][132];
    for (int idx = tid; idx < 64 * 132; idx += 256) {
        int row = idx / 132, col = idx % 132;
        if (col < 129) Wl[row][col] = W[((size_t)b * 64 + row) * 132 + col];
    }
    __syncthreads();
    bf16x8 ahi[4], alo[4];
    #pragma unroll
    for (int kt = 0; kt < 4; ++kt) {
        float tmp[8];
        *(float4*)&tmp[0] = *(float4*)&Wl[16 * wv + lm][kt * 32 + lg * 8];
        *(float4*)&tmp[4] = *(float4*)&Wl[16 * wv + lm][kt * 32 + lg * 8 + 4];
        #pragma unroll
        for (int i = 0; i < 8; ++i) {
            unsigned short h = f2bf(tmp[i]);
            ahi[kt][i] = (short)h;
            alo[kt][i] = (short)f2bf(tmp[i] - bf2f(h));
        }
    }
    float bias[4];
    #pragma unroll
    for (int j = 0; j < 4; ++j) bias[j] = Wl[16 * wv + lg * 4 + j][128];
    f32x4 acc[8] = {};
    unsigned short* ftb = FT + (size_t)b * N * 128;
    int x0 = blk * 128;
    #pragma unroll
    for (int xt = 0; xt < 8; ++xt) {
        int x = x0 + xt * 16 + lm;
        const unsigned short* fp = ftb + (size_t)x * 128 + lg * 8;
        #pragma unroll
        for (int kt = 0; kt < 4; ++kt) {
            bf16x8 bf = *(const bf16x8*)(fp + kt * 32);
            acc[xt] = __builtin_amdgcn_mfma_f32_16x16x32_bf16(ahi[kt], bf, acc[xt], 0, 0, 0);
            acc[xt] = __builtin_amdgcn_mfma_f32_16x16x32_bf16(alo[kt], bf, acc[xt], 0, 0, 0);
        }
    }
    __syncthreads();  // all FT reads complete before ch-cols overwritten
    int r0 = 16 * wv + lg * 4;
    #pragma unroll
    for (int xt = 0; xt < 8; ++xt) {
        int x = x0 + xt * 16 + lm;
        float v[4];
        #pragma unroll
        for (int j = 0; j < 4; ++j) {
            v[j] = acc[xt][j] + bias[j];
            if (act) v[j] = gelu_f(v[j]);
        }
        unsigned short h[4];
        #pragma unroll
        for (int j = 0; j < 4; ++j) h[j] = f2bf(v[j]);
        if (wch) {
            #pragma unroll
            for (int j = 0; j < 4; ++j) cbp[(size_t)(r0 + j) * N + x] = h[j];
        }
        unsigned int* dst = (unsigned int*)(ftb + (size_t)x * 128 + 64 + r0);
        dst[0] = pk(h[0], h[1]);
        dst[1] = pk(h[2], h[3]);
    }
}

// ---- fc1(gelu)+fc2 fused, MFMA from FT ch-cols ----
__global__ __launch_bounds__(256) void k_fc12(const unsigned short* __restrict__ FT, const float* __restrict__ w1,
                                              const float* __restrict__ b1, const float* __restrict__ w2,
                                              const float* __restrict__ b2, float* __restrict__ out, int N) {
    int b = blockIdx.y, blk = blockIdx.x, tid = threadIdx.x;
    int lane = tid & 63, wv = tid >> 6;
    int lm = lane & 15, lg = lane >> 4;
    int f0 = wv * 32;
    bf16x8 ahi[2][2], alo[2][2];
    #pragma unroll
    for (int ft = 0; ft < 2; ++ft)
        #pragma unroll
        for (int kt = 0; kt < 2; ++kt) {
            const float* wp = w1 + (size_t)(f0 + ft * 16 + lm) * 64 + kt * 32 + lg * 8;
            float tmp[8];
            *(float4*)&tmp[0] = *(const float4*)wp;
            *(float4*)&tmp[4] = *(const float4*)(wp + 4);
            #pragma unroll
            for (int i = 0; i < 8; ++i) {
                unsigned short h = f2bf(tmp[i]);
                ahi[ft][kt][i] = (short)h;
                alo[ft][kt][i] = (short)f2bf(tmp[i] - bf2f(h));
            }
        }
    float b1v[2][4], w2v[2][4];
    #pragma unroll
    for (int ft = 0; ft < 2; ++ft)
        #pragma unroll
        for (int j = 0; j < 4; ++j) {
            int f = f0 + ft * 16 + lg * 4 + j;
            b1v[ft][j] = b1[f];
            w2v[ft][j] = w2[f];
        }
    f32x4 acc[8][2] = {};
    const unsigned short* ftb = FT + (size_t)b * N * 128;
    int x0 = blk * 128;
    #pragma unroll
    for (int xt = 0; xt < 8; ++xt) {
        const unsigned short* fp = ftb + (size_t)(x0 + xt * 16 + lm) * 128 + 64 + lg * 8;
        bf16x8 bf0 = *(const bf16x8*)fp;
        bf16x8 bf1 = *(const bf16x8*)(fp + 32);
        #pragma unroll
        for (int ft = 0; ft < 2; ++ft) {
            acc[xt][ft] = __builtin_amdgcn_mfma_f32_16x16x32_bf16(ahi[ft][0], bf0, acc[xt][ft], 0, 0, 0);
            acc[xt][ft] = __builtin_amdgcn_mfma_f32_16x16x32_bf16(alo[ft][0], bf0, acc[xt][ft], 0, 0, 0);
            acc[xt][ft] = __builtin_amdgcn_mfma_f32_16x16x32_bf16(ahi[ft][1], bf1, acc[xt][ft], 0, 0, 0);
            acc[xt][ft] = __builtin_amdgcn_mfma_f32_16x16x32_bf16(alo[ft][1], bf1, acc[xt][ft], 0, 0, 0);
        }
    }
    __shared__ float red[4][8][16];
    #pragma unroll
    for (int xt = 0; xt < 8; ++xt) {
        float s = 0.f;
        #pragma unroll
        for (int ft = 0; ft < 2; ++ft)
            #pragma unroll
            for (int j = 0; j < 4; ++j) {
                float v = acc[xt][ft][j] + b1v[ft][j];
                s += w2v[ft][j] * gelu_f(v);
            }
        s += __shfl_xor(s, 16, 64);
        s += __shfl_xor(s, 32, 64);
        if (lg == 0) red[wv][xt][lm] = s;
    }
    __syncthreads();
    if (tid < 128) {
        int xt = tid >> 4, lmm = tid & 15;
        float s = b2[0] + red[0][xt][lmm] + red[1][xt][lmm] + red[2][xt][lmm] + red[3][xt][lmm];
        out[(size_t)b * N + x0 + tid] = s;
    }
}

extern "C" void kernel_launch(void* const* d_in, const int* in_sizes, int n_in,
                              void* d_out, int out_size, void* d_ws, size_t ws_size,
                              hipStream_t stream) {
    const float* u_in = (const float*)d_in[0];
    const float* v_in = (const float*)d_in[1];
    const float* nodes_u = (const float*)d_in[3];
    const float* nodes_v = (const float*)d_in[4];
    const float* nwu = (const float*)d_in[5];
    const float* nwv = (const float*)d_in[6];
    const float* modes = (const float*)d_in[7];
    const float* latent = (const float*)d_in[8];
    const float* fc0uw = (const float*)d_in[9];
    const float* fc0ub = (const float*)d_in[10];
    const float* fc0vw = (const float*)d_in[11];
    const float* fc0vb = (const float*)d_in[12];
    const float* ewc = (const float*)d_in[13];
    const float* ews = (const float*)d_in[14];
    const float* ew0 = (const float*)d_in[15];
    const float* uwc = (const float*)d_in[16];
    const float* uws = (const float*)d_in[17];
    const float* uw0 = (const float*)d_in[18];
    const float* vwc = (const float*)d_in[19];
    const float* vws = (const float*)d_in[20];
    const float* vw0 = (const float*)d_in[21];
    const float* wsuw = (const float*)d_in[22];
    const float* wsub = (const float*)d_in[23];
    const float* wsvw = (const float*)d_in[24];
    const float* wsvb = (const float*)d_in[25];
    const float* fc1w = (const float*)d_in[26];
    const float* fc1b = (const float*)d_in[27];
    const float* fc2w = (const float*)d_in[28];
    const float* fc2b = (const float*)d_in[29];
    float* out = (float*)d_out;

    const int B = 4, NU = 65536, NV = 16384;
    const int CH_U = 256, CH_V = 128;

    unsigned short* FT_u = (unsigned short*)d_ws;
    unsigned short* FT_v = FT_u + (size_t)B * NU * 128;
    unsigned short* wbb_u = FT_v + (size_t)B * NV * 128;
    unsigned short* wbb_v = wbb_u + (size_t)B * 65 * NU;
    unsigned short* chbf_u = wbb_v + (size_t)B * 65 * NV;
    unsigned short* chbf_v = chbf_u + (size_t)B * 64 * NU;
    float* part_u = (float*)(chbf_v + (size_t)B * 64 * NV);
    float* part_v = part_u + (size_t)B * CH_U * 64 * 66;
    float* momu = part_v + (size_t)B * CH_V * 64 * 66;
    float* momv = momu + B * 64 * 66;
    float* Wu = momv + B * 64 * 66;
    float* Wv = Wu + B * 64 * 132;
    float* wT = Wv + B * 64 * 132;
    size_t need_T = (size_t)((char*)(wT + 6 * 393216) - (char*)d_ws);
    int use_T = (ws_size >= need_T) ? 1 : 0;

    k_prep<<<dim3(NU / 256, B), 256, 0, stream>>>(nodes_u, modes, latent, nwu, u_in, fc0uw, fc0ub,
                                                  FT_u, wbb_u, chbf_u, NU, 2);
    k_prep<<<dim3(NV / 256, B), 256, 0, stream>>>(nodes_v, modes, latent, nwv, v_in, fc0vw, fc0vb,
                                                  FT_v, wbb_v, chbf_v, NV, 3);
    if (use_T)
        k_tw<<<dim3(192, 6), 256, 0, stream>>>(ewc, ews, uwc, uws, vwc, vws, wT);

    for (int l = 0; l < 3; ++l) {
        int do_v = (l < 2) ? 1 : 0;
        k_analysis2<<<dim3(CH_U + CH_V, B), 256, 0, stream>>>(chbf_u, wbb_u, chbf_v, wbb_v,
                                                              part_u, part_v, NU, NV, CH_U, CH_V);
        k_reduce2<<<dim3(17, 2 * B), 256, 0, stream>>>(part_u, part_v, momu, momv, CH_U, CH_V, B);
        if (use_T) {
            k_buildW<<<dim3(33, B), 64, 0, stream>>>(momu, momv,
                wT + 0 * 393216 + l * 131072, wT + 1 * 393216 + l * 131072, ew0 + (size_t)l * 64 * 64,
                wT + 2 * 393216 + l * 131072, wT + 3 * 393216 + l * 131072, uw0 + (size_t)l * 64 * 64,
                wT + 4 * 393216 + l * 131072, wT + 5 * 393216 + l * 131072, vw0 + (size_t)l * 64 * 64,
                wsuw + l * 64 * 64, wsub + l * 64, wsvw + l * 64 * 64, wsvb + l * 64,
                Wu, Wv, do_v);
        } else {
            k_buildW_slow<<<dim3(33, B), 64, 0, stream>>>(momu, momv,
                ewc + (size_t)l * 64 * 64 * 32, ews + (size_t)l * 64 * 64 * 32, ew0 + (size_t)l * 64 * 64,
                uwc + (size_t)l * 64 * 64 * 32, uws + (size_t)l * 64 * 64 * 32, uw0 + (size_t)l * 64 * 64,
                vwc + (size_t)l * 64 * 64 * 32, vws + (size_t)l * 64 * 64 * 32, vw0 + (size_t)l * 64 * 64,
                wsuw + l * 64 * 64, wsub + l * 64, wsvw + l * 64 * 64, wsvb + l * 64,
                Wu, Wv, do_v);
        }
        int nbu = NU / 128;
        int nbx = nbu + (do_v ? NV / 128 : 0);
        k_synth2<<<dim3(nbx, B), 256, 0, stream>>>(Wu, Wv, FT_u, FT_v, chbf_u, chbf_v,
                                                   NU, NV, nbu, do_v, do_v);
    }
    k_fc12<<<dim3(NU / 128, B), 256, 0, stream>>>(FT_u, fc1w, fc1b, fc2w, fc2b, out, NU);
}

// Round 7
// 624.230 us; speedup vs baseline: 3.7347x; 1.1129x over previous
//
#include <hip/hip_runtime.h>
#include <math.h>

#define PI2 6.283185307179586f

typedef __attribute__((ext_vector_type(8))) short bf16x8;
typedef __attribute__((ext_vector_type(4))) float f32x4;

__device__ __forceinline__ float gelu_f(float x) {
    return 0.5f * x * (1.0f + erff(x * 0.7071067811865476f));
}
__device__ __forceinline__ unsigned short f2bf(float f) {
    unsigned int u = __float_as_uint(f);
    u += 0x7FFFu + ((u >> 16) & 1u);
    return (unsigned short)(u >> 16);
}
__device__ __forceinline__ float bf2f(unsigned short h) {
    return __uint_as_float(((unsigned int)h) << 16);
}
__device__ __forceinline__ unsigned int pk(unsigned short a, unsigned short b) {
    return (unsigned int)a | ((unsigned int)b << 16);
}
// split fp32 weight into bf16 hi (dst[0]) + lo residual (dst[128])
__device__ __forceinline__ void wsplit(float w, unsigned short* dst) {
    unsigned short h = f2bf(w);
    dst[0] = h;
    dst[128] = f2bf(w - bf2f(h));
}

// ---- fused bases + fc0: FT[b][x][128] = [cos32; sin32; ch64] bf16,
//      wbb planes [b][k][x] (k<32 cos*w, 32..63 sin*w, 64 w), chbf planes [b][c][x] ----
__global__ __launch_bounds__(256) void k_prep(const float* __restrict__ nodes, const float* __restrict__ modes,
                                              const float* __restrict__ latent, const float* __restrict__ nw,
                                              const float* __restrict__ inp, const float* __restrict__ fcw,
                                              const float* __restrict__ fcb,
                                              unsigned short* __restrict__ FT, unsigned short* __restrict__ wbb,
                                              unsigned short* __restrict__ chbf, int N, int nin) {
    int b = blockIdx.y;
    int x = blockIdx.x * 256 + threadIdx.x;
    float s0 = 0.5f + 1.5f / (1.0f + expf(-latent[0]));
    float s1 = 0.5f + 1.5f / (1.0f + expf(-latent[1]));
    float n0 = nodes[((size_t)b * N + x) * 2 + 0];
    float n1 = nodes[((size_t)b * N + x) * 2 + 1];
    float wx = nw[(size_t)b * N + x];
    unsigned short* wb = wbb + (size_t)b * 65 * N + x;
    unsigned int row[64];
    #pragma unroll
    for (int k = 0; k < 32; ++k) {
        float m0 = modes[k * 2 + 0] * s0;
        float m1 = modes[k * 2 + 1] * s1;
        float t = PI2 * (n0 * m0 + n1 * m1);
        float s, c;
        sincosf(t, &s, &c);
        unsigned short hc = f2bf(c), hs = f2bf(s);
        if (k & 1) { row[k >> 1] |= ((unsigned int)hc << 16); row[16 + (k >> 1)] |= ((unsigned int)hs << 16); }
        else       { row[k >> 1] = hc;                         row[16 + (k >> 1)] = hs; }
        wb[(size_t)k * N] = f2bf(c * wx);
        wb[(size_t)(32 + k) * N] = f2bf(s * wx);
    }
    wb[(size_t)64 * N] = f2bf(wx);
    // fc0
    float xi[3];
    for (int i = 0; i < nin; ++i) xi[i] = inp[((size_t)b * N + x) * nin + i];
    unsigned short* cb = chbf + (size_t)b * 64 * N + x;
    for (int c = 0; c < 64; ++c) {
        float a = fcb[c];
        for (int i = 0; i < nin; ++i) a += fcw[c * nin + i] * xi[i];
        unsigned short h = f2bf(a);
        cb[(size_t)c * N] = h;
        if (c & 1) row[32 + (c >> 1)] |= ((unsigned int)h << 16);
        else row[32 + (c >> 1)] = h;
    }
    unsigned int* fr = (unsigned int*)(FT + ((size_t)b * N + x) * 128);
    #pragma unroll
    for (int i = 0; i < 64; ++i) fr[i] = row[i];
}

// ---- fused analysis u+v (MFMA): partial[b][chunk][i][col] fp32 ----
__global__ __launch_bounds__(256) void k_analysis2(const unsigned short* __restrict__ chbf_u,
                                                   const unsigned short* __restrict__ wbb_u,
                                                   const unsigned short* __restrict__ chbf_v,
                                                   const unsigned short* __restrict__ wbb_v,
                                                   float* __restrict__ part_u, float* __restrict__ part_v,
                                                   int NU_, int NV_, int chu, int chv) {
    int b = blockIdx.y, bx = blockIdx.x, tid = threadIdx.x;
    const unsigned short *chb, *wb;
    float* pb;
    int N, xlen, chunk;
    if (bx < chu) {
        chunk = bx; N = NU_; xlen = NU_ / chu;
        chb = chbf_u + (size_t)b * 64 * N;
        wb = wbb_u + (size_t)b * 65 * N;
        pb = part_u + (size_t)(b * chu + chunk) * 64 * 66;
    } else {
        chunk = bx - chu; N = NV_; xlen = NV_ / chv;
        chb = chbf_v + (size_t)b * 64 * N;
        wb = wbb_v + (size_t)b * 65 * N;
        pb = part_v + (size_t)(b * chv + chunk) * 64 * 66;
    }
    int lane = tid & 63, wv = tid >> 6;
    int lm = lane & 15, lg = lane >> 4;
    int ro = wv * 16;
    int x0 = chunk * xlen;
    f32x4 acc[5] = {};
    for (int x = x0; x < x0 + xlen; x += 32) {
        bf16x8 a = *(const bf16x8*)(chb + (size_t)(ro + lm) * N + x + lg * 8);
        #pragma unroll
        for (int ct = 0; ct < 4; ++ct) {
            bf16x8 bf = *(const bf16x8*)(wb + (size_t)(ct * 16 + lm) * N + x + lg * 8);
            acc[ct] = __builtin_amdgcn_mfma_f32_16x16x32_bf16(a, bf, acc[ct], 0, 0, 0);
        }
        bf16x8 wf = *(const bf16x8*)(wb + (size_t)64 * N + x + lg * 8);
        acc[4] = __builtin_amdgcn_mfma_f32_16x16x32_bf16(a, wf, acc[4], 0, 0, 0);
    }
    #pragma unroll
    for (int ct = 0; ct < 4; ++ct)
        #pragma unroll
        for (int j = 0; j < 4; ++j)
            pb[(ro + lg * 4 + j) * 66 + ct * 16 + lm] = acc[ct][j];
    if (lm == 0) {
        #pragma unroll
        for (int j = 0; j < 4; ++j) pb[(ro + lg * 4 + j) * 66 + 64] = acc[4][j];
    }
}

// ---- fused reduce u+v -> mom[b][i][col] stride 66 ----
__global__ void k_reduce2(const float* __restrict__ part_u, const float* __restrict__ part_v,
                          float* __restrict__ momu, float* __restrict__ momv, int chu, int chv, int B_) {
    int by = blockIdx.y;
    const float* p;
    float* m;
    int nch, b;
    if (by < B_) { b = by; p = part_u; m = momu; nch = chu; }
    else { b = by - B_; p = part_v; m = momv; nch = chv; }
    int e = blockIdx.x * 256 + threadIdx.x;
    if (e >= 64 * 65) return;
    int row = e / 65, col = e % 65;
    const float* pp = p + ((size_t)(b * nch) * 64 + row) * 66 + col;
    float s = 0.f;
    #pragma unroll 4
    for (int c = 0; c < nch; ++c)
        s += pp[(size_t)c * 64 * 66];
    m[((size_t)b * 64 + row) * 66 + col] = s;
}

// ---- transpose weights (l,i,o,k)->(l,k,i,o) ----
__global__ __launch_bounds__(256) void k_tw(const float* __restrict__ e_c, const float* __restrict__ e_s,
                                            const float* __restrict__ u_c, const float* __restrict__ u_s,
                                            const float* __restrict__ v_c, const float* __restrict__ v_s,
                                            float* __restrict__ oT) {
    int li = blockIdx.x;
    int a = blockIdx.y;
    const float* in;
    switch (a) {
        case 0: in = e_c; break;
        case 1: in = e_s; break;
        case 2: in = u_c; break;
        case 3: in = u_s; break;
        case 4: in = v_c; break;
        default: in = v_s; break;
    }
    float* outp = oT + (size_t)a * 393216;
    int l = li >> 6, i = li & 63;
    __shared__ float t[32][65];
    int tid = threadIdx.x;
    const float* ib = in + (size_t)l * 131072 + (size_t)i * 2048;
    #pragma unroll
    for (int r = 0; r < 8; ++r) {
        int e = r * 256 + tid;
        t[e & 31][e >> 5] = ib[e];
    }
    __syncthreads();
    float* ob = outp + (size_t)l * 131072 + (size_t)i * 64;
    #pragma unroll
    for (int r = 0; r < 8; ++r) {
        int e = r * 256 + tid;
        ob[(size_t)(e >> 6) * 4096 + (e & 63)] = t[e >> 6][e & 63];
    }
}

// ---- buildW -> WBf[b][o][hi128|lo128] bf16 + bias[b][o] fp32 (split at write) ----
__global__ void k_buildW(const float* __restrict__ momu, const float* __restrict__ momv,
                         const float* __restrict__ ecT, const float* __restrict__ esT, const float* __restrict__ ew0,
                         const float* __restrict__ ucT, const float* __restrict__ usT, const float* __restrict__ uw0,
                         const float* __restrict__ vcT, const float* __restrict__ vsT, const float* __restrict__ vw0,
                         const float* __restrict__ wsuw, const float* __restrict__ wsub,
                         const float* __restrict__ wsvw, const float* __restrict__ wsvb,
                         unsigned short* __restrict__ WuBf, unsigned short* __restrict__ WvBf,
                         float* __restrict__ biasU, float* __restrict__ biasV, int do_v) {
    int b = blockIdx.y, j = blockIdx.x, o = threadIdx.x;
    const float* mu = momu + (size_t)b * 64 * 66;
    const float* mv = momv + (size_t)b * 64 * 66;
    unsigned short* Wub = WuBf + ((size_t)b * 64 + o) * 256;
    unsigned short* Wvb = WvBf + ((size_t)b * 64 + o) * 256;
    if (j < 32) {
        int k = j;
        const float* ec = ecT + (size_t)k * 4096;
        const float* es = esT + (size_t)k * 4096;
        const float* uc = ucT + (size_t)k * 4096;
        const float* us = usT + (size_t)k * 4096;
        const float* vc = vcT + (size_t)k * 4096;
        const float* vs = vsT + (size_t)k * 4096;
        float fcu = 0, fsu = 0, fcv = 0, fsv = 0;
        for (int i = 0; i < 64; ++i) {
            float Scv = mv[i * 66 + k], Ssv = mv[i * 66 + 32 + k];
            float Scu = mu[i * 66 + k], Ssu = mu[i * 66 + 32 + k];
            int wi = i * 64 + o;
            float e_c = ec[wi], e_s = es[wi];
            float u_c = uc[wi], u_s = us[wi];
            fcu += Scv * e_c + Ssv * e_s + Scu * u_c + Ssu * u_s;
            fsu += Scv * e_s - Ssv * e_c + Scu * u_s - Ssu * u_c;
            if (do_v) {
                float v_c = vc[wi], v_s = vs[wi];
                fcv += Scv * v_c + Ssv * v_s;
                fsv += Scv * v_s - Ssv * v_c;
            }
        }
        wsplit(2.f * fcu, Wub + k);
        wsplit(-2.f * fsu, Wub + 32 + k);
        if (do_v) {
            wsplit(2.f * fcv, Wvb + k);
            wsplit(-2.f * fsv, Wvb + 32 + k);
        }
    } else {
        for (int c = 0; c < 64; ++c) wsplit(wsuw[o * 64 + c], Wub + 64 + c);
        float f0u = 0;
        for (int i = 0; i < 64; ++i)
            f0u += mv[i * 66 + 64] * ew0[i * 64 + o] + mu[i * 66 + 64] * uw0[i * 64 + o];
        biasU[b * 64 + o] = f0u + wsub[o];
        if (do_v) {
            for (int c = 0; c < 64; ++c) wsplit(wsvw[o * 64 + c], Wvb + 64 + c);
            float f0v = 0;
            for (int i = 0; i < 64; ++i) f0v += mv[i * 66 + 64] * vw0[i * 64 + o];
            biasV[b * 64 + o] = f0v + wsvb[o];
        }
    }
}

// ---- fallback buildW (original weight layout) ----
__global__ void k_buildW_slow(const float* __restrict__ momu, const float* __restrict__ momv,
                              const float* __restrict__ ewc, const float* __restrict__ ews, const float* __restrict__ ew0,
                              const float* __restrict__ uwc, const float* __restrict__ uws, const float* __restrict__ uw0,
                              const float* __restrict__ vwc, const float* __restrict__ vws, const float* __restrict__ vw0,
                              const float* __restrict__ wsuw, const float* __restrict__ wsub,
                              const float* __restrict__ wsvw, const float* __restrict__ wsvb,
                              unsigned short* __restrict__ WuBf, unsigned short* __restrict__ WvBf,
                              float* __restrict__ biasU, float* __restrict__ biasV, int do_v) {
    int b = blockIdx.y, j = blockIdx.x, o = threadIdx.x;
    const float* mu = momu + (size_t)b * 64 * 66;
    const float* mv = momv + (size_t)b * 64 * 66;
    unsigned short* Wub = WuBf + ((size_t)b * 64 + o) * 256;
    unsigned short* Wvb = WvBf + ((size_t)b * 64 + o) * 256;
    if (j < 32) {
        int k = j;
        float fcu = 0, fsu = 0, fcv = 0, fsv = 0;
        for (int i = 0; i < 64; ++i) {
            float Scv = mv[i * 66 + k], Ssv = mv[i * 66 + 32 + k];
            float Scu = mu[i * 66 + k], Ssu = mu[i * 66 + 32 + k];
            int wi = (i * 64 + o) * 32 + k;
            float ec = ewc[wi], es = ews[wi];
            float uc = uwc[wi], us = uws[wi];
            fcu += Scv * ec + Ssv * es + Scu * uc + Ssu * us;
            fsu += Scv * es - Ssv * ec + Scu * us - Ssu * uc;
            if (do_v) {
                float vc = vwc[wi], vs = vws[wi];
                fcv += Scv * vc + Ssv * vs;
                fsv += Scv * vs - Ssv * vc;
            }
        }
        wsplit(2.f * fcu, Wub + k);
        wsplit(-2.f * fsu, Wub + 32 + k);
        if (do_v) {
            wsplit(2.f * fcv, Wvb + k);
            wsplit(-2.f * fsv, Wvb + 32 + k);
        }
    } else {
        for (int c = 0; c < 64; ++c) wsplit(wsuw[o * 64 + c], Wub + 64 + c);
        float f0u = 0;
        for (int i = 0; i < 64; ++i)
            f0u += mv[i * 66 + 64] * ew0[i * 64 + o] + mu[i * 66 + 64] * uw0[i * 64 + o];
        biasU[b * 64 + o] = f0u + wsub[o];
        if (do_v) {
            for (int c = 0; c < 64; ++c) wsplit(wsvw[o * 64 + c], Wvb + 64 + c);
            float f0v = 0;
            for (int i = 0; i < 64; ++i) f0v += mv[i * 66 + 64] * vw0[i * 64 + o];
            biasV[b * 64 + o] = f0v + wsvb[o];
        }
    }
}

// ---- fused synthesis u+v (MFMA, no LDS): out = act(Wbf(hi+lo) . FT[x][128] + bias) ----
__global__ __launch_bounds__(256) void k_synth2(const unsigned short* __restrict__ WuBf,
                                                const unsigned short* __restrict__ WvBf,
                                                const float* __restrict__ biasU, const float* __restrict__ biasV,
                                                unsigned short* FTu, unsigned short* FTv,
                                                unsigned short* __restrict__ cbu, unsigned short* __restrict__ cbv,
                                                int NU_, int NV_, int nbu, int act_u, int wch_u) {
    int bx = blockIdx.x, b = blockIdx.y, tid = threadIdx.x;
    const unsigned short* Wb;
    const float* bi;
    unsigned short *FT, *cbp;
    int N, act, wch, blk;
    if (bx < nbu) { Wb = WuBf; bi = biasU; FT = FTu; cbp = cbu; N = NU_; act = act_u; wch = wch_u; blk = bx; }
    else { Wb = WvBf; bi = biasV; FT = FTv; cbp = cbv; N = NV_; act = 1; wch = 1; blk = bx - nbu; }
    int lane = tid & 63, wv = tid >> 6;
    int lm = lane & 15, lg = lane >> 4;
    const unsigned short* Wrow = Wb + ((size_t)b * 64 + 16 * wv + lm) * 256;
    bf16x8 ahi[4], alo[4];
    #pragma unroll
    for (int kt = 0; kt < 4; ++kt) {
        ahi[kt] = *(const bf16x8*)(Wrow + kt * 32 + lg * 8);
        alo[kt] = *(const bf16x8*)(Wrow + 128 + kt * 32 + lg * 8);
    }
    float bias[4];
    #pragma unroll
    for (int j = 0; j < 4; ++j) bias[j] = bi[b * 64 + 16 * wv + lg * 4 + j];
    f32x4 acc[8] = {};
    unsigned short* ftb = FT + (size_t)b * N * 128;
    int x0 = blk * 128;
    #pragma unroll
    for (int xt = 0; xt < 8; ++xt) {
        int x = x0 + xt * 16 + lm;
        const unsigned short* fp = ftb + (size_t)x * 128 + lg * 8;
        #pragma unroll
        for (int kt = 0; kt < 4; ++kt) {
            bf16x8 bf = *(const bf16x8*)(fp + kt * 32);
            acc[xt] = __builtin_amdgcn_mfma_f32_16x16x32_bf16(ahi[kt], bf, acc[xt], 0, 0, 0);
            acc[xt] = __builtin_amdgcn_mfma_f32_16x16x32_bf16(alo[kt], bf, acc[xt], 0, 0, 0);
        }
    }
    __syncthreads();  // all FT reads (all waves) complete before ch-cols overwritten
    int r0 = 16 * wv + lg * 4;
    #pragma unroll
    for (int xt = 0; xt < 8; ++xt) {
        int x = x0 + xt * 16 + lm;
        float v[4];
        #pragma unroll
        for (int j = 0; j < 4; ++j) {
            v[j] = acc[xt][j] + bias[j];
            if (act) v[j] = gelu_f(v[j]);
        }
        unsigned short h[4];
        #pragma unroll
        for (int j = 0; j < 4; ++j) h[j] = f2bf(v[j]);
        if (wch) {
            #pragma unroll
            for (int j = 0; j < 4; ++j) cbp[(size_t)(r0 + j) * N + x] = h[j];
        }
        unsigned int* dst = (unsigned int*)(ftb + (size_t)x * 128 + 64 + r0);
        dst[0] = pk(h[0], h[1]);
        dst[1] = pk(h[2], h[3]);
    }
}

// ---- fc1(gelu)+fc2 fused, MFMA from FT ch-cols ----
__global__ __launch_bounds__(256) void k_fc12(const unsigned short* __restrict__ FT, const float* __restrict__ w1,
                                              const float* __restrict__ b1, const float* __restrict__ w2,
                                              const float* __restrict__ b2, float* __restrict__ out, int N) {
    int b = blockIdx.y, blk = blockIdx.x, tid = threadIdx.x;
    int lane = tid & 63, wv = tid >> 6;
    int lm = lane & 15, lg = lane >> 4;
    int f0 = wv * 32;
    bf16x8 ahi[2][2], alo[2][2];
    #pragma unroll
    for (int ft = 0; ft < 2; ++ft)
        #pragma unroll
        for (int kt = 0; kt < 2; ++kt) {
            const float* wp = w1 + (size_t)(f0 + ft * 16 + lm) * 64 + kt * 32 + lg * 8;
            float tmp[8];
            *(float4*)&tmp[0] = *(const float4*)wp;
            *(float4*)&tmp[4] = *(const float4*)(wp + 4);
            #pragma unroll
            for (int i = 0; i < 8; ++i) {
                unsigned short h = f2bf(tmp[i]);
                ahi[ft][kt][i] = (short)h;
                alo[ft][kt][i] = (short)f2bf(tmp[i] - bf2f(h));
            }
        }
    float b1v[2][4], w2v[2][4];
    #pragma unroll
    for (int ft = 0; ft < 2; ++ft)
        #pragma unroll
        for (int j = 0; j < 4; ++j) {
            int f = f0 + ft * 16 + lg * 4 + j;
            b1v[ft][j] = b1[f];
            w2v[ft][j] = w2[f];
        }
    f32x4 acc[8][2] = {};
    const unsigned short* ftb = FT + (size_t)b * N * 128;
    int x0 = blk * 128;
    #pragma unroll
    for (int xt = 0; xt < 8; ++xt) {
        const unsigned short* fp = ftb + (size_t)(x0 + xt * 16 + lm) * 128 + 64 + lg * 8;
        bf16x8 bf0 = *(const bf16x8*)fp;
        bf16x8 bf1 = *(const bf16x8*)(fp + 32);
        #pragma unroll
        for (int ft = 0; ft < 2; ++ft) {
            acc[xt][ft] = __builtin_amdgcn_mfma_f32_16x16x32_bf16(ahi[ft][0], bf0, acc[xt][ft], 0, 0, 0);
            acc[xt][ft] = __builtin_amdgcn_mfma_f32_16x16x32_bf16(alo[ft][0], bf0, acc[xt][ft], 0, 0, 0);
            acc[xt][ft] = __builtin_amdgcn_mfma_f32_16x16x32_bf16(ahi[ft][1], bf1, acc[xt][ft], 0, 0, 0);
            acc[xt][ft] = __builtin_amdgcn_mfma_f32_16x16x32_bf16(alo[ft][1], bf1, acc[xt][ft], 0, 0, 0);
        }
    }
    __shared__ float red[4][8][16];
    #pragma unroll
    for (int xt = 0; xt < 8; ++xt) {
        float s = 0.f;
        #pragma unroll
        for (int ft = 0; ft < 2; ++ft)
            #pragma unroll
            for (int j = 0; j < 4; ++j) {
                float v = acc[xt][ft][j] + b1v[ft][j];
                s += w2v[ft][j] * gelu_f(v);
            }
        s += __shfl_xor(s, 16, 64);
        s += __shfl_xor(s, 32, 64);
        if (lg == 0) red[wv][xt][lm] = s;
    }
    __syncthreads();
    if (tid < 128) {
        int xt = tid >> 4, lmm = tid & 15;
        float s = b2[0] + red[0][xt][lmm] + red[1][xt][lmm] + red[2][xt][lmm] + red[3][xt][lmm];
        out[(size_t)b * N + x0 + tid] = s;
    }
}

extern "C" void kernel_launch(void* const* d_in, const int* in_sizes, int n_in,
                              void* d_out, int out_size, void* d_ws, size_t ws_size,
                              hipStream_t stream) {
    const float* u_in = (const float*)d_in[0];
    const float* v_in = (const float*)d_in[1];
    const float* nodes_u = (const float*)d_in[3];
    const float* nodes_v = (const float*)d_in[4];
    const float* nwu = (const float*)d_in[5];
    const float* nwv = (const float*)d_in[6];
    const float* modes = (const float*)d_in[7];
    const float* latent = (const float*)d_in[8];
    const float* fc0uw = (const float*)d_in[9];
    const float* fc0ub = (const float*)d_in[10];
    const float* fc0vw = (const float*)d_in[11];
    const float* fc0vb = (const float*)d_in[12];
    const float* ewc = (const float*)d_in[13];
    const float* ews = (const float*)d_in[14];
    const float* ew0 = (const float*)d_in[15];
    const float* uwc = (const float*)d_in[16];
    const float* uws = (const float*)d_in[17];
    const float* uw0 = (const float*)d_in[18];
    const float* vwc = (const float*)d_in[19];
    const float* vws = (const float*)d_in[20];
    const float* vw0 = (const float*)d_in[21];
    const float* wsuw = (const float*)d_in[22];
    const float* wsub = (const float*)d_in[23];
    const float* wsvw = (const float*)d_in[24];
    const float* wsvb = (const float*)d_in[25];
    const float* fc1w = (const float*)d_in[26];
    const float* fc1b = (const float*)d_in[27];
    const float* fc2w = (const float*)d_in[28];
    const float* fc2b = (const float*)d_in[29];
    float* out = (float*)d_out;

    const int B = 4, NU = 65536, NV = 16384;
    const int CH_U = 256, CH_V = 128;

    unsigned short* FT_u = (unsigned short*)d_ws;
    unsigned short* FT_v = FT_u + (size_t)B * NU * 128;
    unsigned short* wbb_u = FT_v + (size_t)B * NV * 128;
    unsigned short* wbb_v = wbb_u + (size_t)B * 65 * NU;
    unsigned short* chbf_u = wbb_v + (size_t)B * 65 * NV;
    unsigned short* chbf_v = chbf_u + (size_t)B * 64 * NU;
    float* part_u = (float*)(chbf_v + (size_t)B * 64 * NV);
    float* part_v = part_u + (size_t)B * CH_U * 64 * 66;
    float* momu = part_v + (size_t)B * CH_V * 64 * 66;
    float* momv = momu + B * 64 * 66;
    unsigned short* WuBf = (unsigned short*)(momv + B * 64 * 66);
    unsigned short* WvBf = WuBf + (size_t)B * 64 * 256;
    float* biasU = (float*)(WvBf + (size_t)B * 64 * 256);
    float* biasV = biasU + B * 64;
    float* wT = biasV + B * 64;
    size_t need_T = (size_t)((char*)(wT + 6 * 393216) - (char*)d_ws);
    int use_T = (ws_size >= need_T) ? 1 : 0;

    k_prep<<<dim3(NU / 256, B), 256, 0, stream>>>(nodes_u, modes, latent, nwu, u_in, fc0uw, fc0ub,
                                                  FT_u, wbb_u, chbf_u, NU, 2);
    k_prep<<<dim3(NV / 256, B), 256, 0, stream>>>(nodes_v, modes, latent, nwv, v_in, fc0vw, fc0vb,
                                                  FT_v, wbb_v, chbf_v, NV, 3);
    if (use_T)
        k_tw<<<dim3(192, 6), 256, 0, stream>>>(ewc, ews, uwc, uws, vwc, vws, wT);

    for (int l = 0; l < 3; ++l) {
        int do_v = (l < 2) ? 1 : 0;
        k_analysis2<<<dim3(CH_U + CH_V, B), 256, 0, stream>>>(chbf_u, wbb_u, chbf_v, wbb_v,
                                                              part_u, part_v, NU, NV, CH_U, CH_V);
        k_reduce2<<<dim3(17, 2 * B), 256, 0, stream>>>(part_u, part_v, momu, momv, CH_U, CH_V, B);
        if (use_T) {
            k_buildW<<<dim3(33, B), 64, 0, stream>>>(momu, momv,
                wT + 0 * 393216 + l * 131072, wT + 1 * 393216 + l * 131072, ew0 + (size_t)l * 64 * 64,
                wT + 2 * 393216 + l * 131072, wT + 3 * 393216 + l * 131072, uw0 + (size_t)l * 64 * 64,
                wT + 4 * 393216 + l * 131072, wT + 5 * 393216 + l * 131072, vw0 + (size_t)l * 64 * 64,
                wsuw + l * 64 * 64, wsub + l * 64, wsvw + l * 64 * 64, wsvb + l * 64,
                WuBf, WvBf, biasU, biasV, do_v);
        } else {
            k_buildW_slow<<<dim3(33, B), 64, 0, stream>>>(momu, momv,
                ewc + (size_t)l * 64 * 64 * 32, ews + (size_t)l * 64 * 64 * 32, ew0 + (size_t)l * 64 * 64,
                uwc + (size_t)l * 64 * 64 * 32, uws + (size_t)l * 64 * 64 * 32, uw0 + (size_t)l * 64 * 64,
                vwc + (size_t)l * 64 * 64 * 32, vws + (size_t)l * 64 * 64 * 32, vw0 + (size_t)l * 64 * 64,
                wsuw + l * 64 * 64, wsub + l * 64, wsvw + l * 64 * 64, wsvb + l * 64,
                WuBf, WvBf, biasU, biasV, do_v);
        }
        int nbu = NU / 128;
        int nbx = nbu + (do_v ? NV / 128 : 0);
        k_synth2<<<dim3(nbx, B), 256, 0, stream>>>(WuBf, WvBf, biasU, biasV, FT_u, FT_v, chbf_u, chbf_v,
                                                   NU, NV, nbu, do_v, do_v);
    }
    k_fc12<<<dim3(NU / 128, B), 256, 0, stream>>>(FT_u, fc1w, fc1b, fc2w, fc2b, out, NU);
}

// Round 8
// 538.612 us; speedup vs baseline: 4.3284x; 1.1590x over previous
//
#include <hip/hip_runtime.h>
#include <math.h>

#define PI2 6.283185307179586f

typedef __attribute__((ext_vector_type(8))) short bf16x8;
typedef __attribute__((ext_vector_type(4))) float f32x4;

__device__ __forceinline__ float gelu_f(float x) {
    return 0.5f * x * (1.0f + erff(x * 0.7071067811865476f));
}
__device__ __forceinline__ unsigned short f2bf(float f) {
    unsigned int u = __float_as_uint(f);
    u += 0x7FFFu + ((u >> 16) & 1u);
    return (unsigned short)(u >> 16);
}
__device__ __forceinline__ float bf2f(unsigned short h) {
    return __uint_as_float(((unsigned int)h) << 16);
}
__device__ __forceinline__ unsigned int pk(unsigned short a, unsigned short b) {
    return (unsigned int)a | ((unsigned int)b << 16);
}
// split fp32 weight into bf16 hi (dst[0]) + lo residual (dst[128])
__device__ __forceinline__ void wsplit(float w, unsigned short* dst) {
    unsigned short h = f2bf(w);
    dst[0] = h;
    dst[128] = f2bf(w - bf2f(h));
}

// ---- fused bases + fc0: FT[b][x][128] = [cos32; sin32; ch64] bf16,
//      wbb planes [b][k][x] (k<32 cos*w, 32..63 sin*w, 64 w), chbf planes [b][c][x].
//      NIN templated + full unroll so row[] stays in VGPRs (no scratch spill). ----
template<int NIN>
__global__ __launch_bounds__(256) void k_prep(const float* __restrict__ nodes, const float* __restrict__ modes,
                                              const float* __restrict__ latent, const float* __restrict__ nw,
                                              const float* __restrict__ inp, const float* __restrict__ fcw,
                                              const float* __restrict__ fcb,
                                              unsigned short* __restrict__ FT, unsigned short* __restrict__ wbb,
                                              unsigned short* __restrict__ chbf, int N) {
    int b = blockIdx.y;
    int x = blockIdx.x * 256 + threadIdx.x;
    float s0 = 0.5f + 1.5f / (1.0f + expf(-latent[0]));
    float s1 = 0.5f + 1.5f / (1.0f + expf(-latent[1]));
    float n0 = nodes[((size_t)b * N + x) * 2 + 0];
    float n1 = nodes[((size_t)b * N + x) * 2 + 1];
    float wx = nw[(size_t)b * N + x];
    unsigned short* wb = wbb + (size_t)b * 65 * N + x;
    unsigned int row[64];
    #pragma unroll
    for (int k = 0; k < 32; ++k) {
        float m0 = modes[k * 2 + 0] * s0;
        float m1 = modes[k * 2 + 1] * s1;
        float t = PI2 * (n0 * m0 + n1 * m1);
        float s, c;
        sincosf(t, &s, &c);
        unsigned short hc = f2bf(c), hs = f2bf(s);
        if (k & 1) { row[k >> 1] |= ((unsigned int)hc << 16); row[16 + (k >> 1)] |= ((unsigned int)hs << 16); }
        else       { row[k >> 1] = hc;                         row[16 + (k >> 1)] = hs; }
        wb[(size_t)k * N] = f2bf(c * wx);
        wb[(size_t)(32 + k) * N] = f2bf(s * wx);
    }
    wb[(size_t)64 * N] = f2bf(wx);
    // fc0 (fully unrolled -> static row[] indices)
    float xi[NIN];
    #pragma unroll
    for (int i = 0; i < NIN; ++i) xi[i] = inp[((size_t)b * N + x) * NIN + i];
    unsigned short* cb = chbf + (size_t)b * 64 * N + x;
    #pragma unroll
    for (int c = 0; c < 64; ++c) {
        float a = fcb[c];
        #pragma unroll
        for (int i = 0; i < NIN; ++i) a += fcw[c * NIN + i] * xi[i];
        unsigned short h = f2bf(a);
        cb[(size_t)c * N] = h;
        if (c & 1) row[32 + (c >> 1)] |= ((unsigned int)h << 16);
        else row[32 + (c >> 1)] = h;
    }
    unsigned int* fr = (unsigned int*)(FT + ((size_t)b * N + x) * 128);
    #pragma unroll
    for (int i = 0; i < 64; ++i) fr[i] = row[i];
}

// ---- fused analysis u+v (MFMA): partial[b][chunk][i][col] fp32 ----
__global__ __launch_bounds__(256) void k_analysis2(const unsigned short* __restrict__ chbf_u,
                                                   const unsigned short* __restrict__ wbb_u,
                                                   const unsigned short* __restrict__ chbf_v,
                                                   const unsigned short* __restrict__ wbb_v,
                                                   float* __restrict__ part_u, float* __restrict__ part_v,
                                                   int NU_, int NV_, int chu, int chv) {
    int b = blockIdx.y, bx = blockIdx.x, tid = threadIdx.x;
    const unsigned short *chb, *wb;
    float* pb;
    int N, xlen, chunk;
    if (bx < chu) {
        chunk = bx; N = NU_; xlen = NU_ / chu;
        chb = chbf_u + (size_t)b * 64 * N;
        wb = wbb_u + (size_t)b * 65 * N;
        pb = part_u + (size_t)(b * chu + chunk) * 64 * 66;
    } else {
        chunk = bx - chu; N = NV_; xlen = NV_ / chv;
        chb = chbf_v + (size_t)b * 64 * N;
        wb = wbb_v + (size_t)b * 65 * N;
        pb = part_v + (size_t)(b * chv + chunk) * 64 * 66;
    }
    int lane = tid & 63, wv = tid >> 6;
    int lm = lane & 15, lg = lane >> 4;
    int ro = wv * 16;
    int x0 = chunk * xlen;
    f32x4 acc[5] = {};
    for (int x = x0; x < x0 + xlen; x += 32) {
        bf16x8 a = *(const bf16x8*)(chb + (size_t)(ro + lm) * N + x + lg * 8);
        #pragma unroll
        for (int ct = 0; ct < 4; ++ct) {
            bf16x8 bf = *(const bf16x8*)(wb + (size_t)(ct * 16 + lm) * N + x + lg * 8);
            acc[ct] = __builtin_amdgcn_mfma_f32_16x16x32_bf16(a, bf, acc[ct], 0, 0, 0);
        }
        bf16x8 wf = *(const bf16x8*)(wb + (size_t)64 * N + x + lg * 8);
        acc[4] = __builtin_amdgcn_mfma_f32_16x16x32_bf16(a, wf, acc[4], 0, 0, 0);
    }
    #pragma unroll
    for (int ct = 0; ct < 4; ++ct)
        #pragma unroll
        for (int j = 0; j < 4; ++j)
            pb[(ro + lg * 4 + j) * 66 + ct * 16 + lm] = acc[ct][j];
    if (lm == 0) {
        #pragma unroll
        for (int j = 0; j < 4; ++j) pb[(ro + lg * 4 + j) * 66 + 64] = acc[4][j];
    }
}

// ---- fused reduce u+v -> mom[b][i][col] stride 66 ----
__global__ void k_reduce2(const float* __restrict__ part_u, const float* __restrict__ part_v,
                          float* __restrict__ momu, float* __restrict__ momv, int chu, int chv, int B_) {
    int by = blockIdx.y;
    const float* p;
    float* m;
    int nch, b;
    if (by < B_) { b = by; p = part_u; m = momu; nch = chu; }
    else { b = by - B_; p = part_v; m = momv; nch = chv; }
    int e = blockIdx.x * 256 + threadIdx.x;
    if (e >= 64 * 65) return;
    int row = e / 65, col = e % 65;
    const float* pp = p + ((size_t)(b * nch) * 64 + row) * 66 + col;
    float s = 0.f;
    #pragma unroll 4
    for (int c = 0; c < nch; ++c)
        s += pp[(size_t)c * 64 * 66];
    m[((size_t)b * 64 + row) * 66 + col] = s;
}

// ---- transpose weights (l,i,o,k)->(l,k,i,o) ----
__global__ __launch_bounds__(256) void k_tw(const float* __restrict__ e_c, const float* __restrict__ e_s,
                                            const float* __restrict__ u_c, const float* __restrict__ u_s,
                                            const float* __restrict__ v_c, const float* __restrict__ v_s,
                                            float* __restrict__ oT) {
    int li = blockIdx.x;
    int a = blockIdx.y;
    const float* in;
    switch (a) {
        case 0: in = e_c; break;
        case 1: in = e_s; break;
        case 2: in = u_c; break;
        case 3: in = u_s; break;
        case 4: in = v_c; break;
        default: in = v_s; break;
    }
    float* outp = oT + (size_t)a * 393216;
    int l = li >> 6, i = li & 63;
    __shared__ float t[32][65];
    int tid = threadIdx.x;
    const float* ib = in + (size_t)l * 131072 + (size_t)i * 2048;
    #pragma unroll
    for (int r = 0; r < 8; ++r) {
        int e = r * 256 + tid;
        t[e & 31][e >> 5] = ib[e];
    }
    __syncthreads();
    float* ob = outp + (size_t)l * 131072 + (size_t)i * 64;
    #pragma unroll
    for (int r = 0; r < 8; ++r) {
        int e = r * 256 + tid;
        ob[(size_t)(e >> 6) * 4096 + (e & 63)] = t[e >> 6][e & 63];
    }
}

// ---- buildW -> WBf[b][o][hi128|lo128] bf16 + bias[b][o] fp32 (split at write) ----
__global__ void k_buildW(const float* __restrict__ momu, const float* __restrict__ momv,
                         const float* __restrict__ ecT, const float* __restrict__ esT, const float* __restrict__ ew0,
                         const float* __restrict__ ucT, const float* __restrict__ usT, const float* __restrict__ uw0,
                         const float* __restrict__ vcT, const float* __restrict__ vsT, const float* __restrict__ vw0,
                         const float* __restrict__ wsuw, const float* __restrict__ wsub,
                         const float* __restrict__ wsvw, const float* __restrict__ wsvb,
                         unsigned short* __restrict__ WuBf, unsigned short* __restrict__ WvBf,
                         float* __restrict__ biasU, float* __restrict__ biasV, int do_v) {
    int b = blockIdx.y, j = blockIdx.x, o = threadIdx.x;
    const float* mu = momu + (size_t)b * 64 * 66;
    const float* mv = momv + (size_t)b * 64 * 66;
    unsigned short* Wub = WuBf + ((size_t)b * 64 + o) * 256;
    unsigned short* Wvb = WvBf + ((size_t)b * 64 + o) * 256;
    if (j < 32) {
        int k = j;
        const float* ec = ecT + (size_t)k * 4096;
        const float* es = esT + (size_t)k * 4096;
        const float* uc = ucT + (size_t)k * 4096;
        const float* us = usT + (size_t)k * 4096;
        const float* vc = vcT + (size_t)k * 4096;
        const float* vs = vsT + (size_t)k * 4096;
        float fcu = 0, fsu = 0, fcv = 0, fsv = 0;
        for (int i = 0; i < 64; ++i) {
            float Scv = mv[i * 66 + k], Ssv = mv[i * 66 + 32 + k];
            float Scu = mu[i * 66 + k], Ssu = mu[i * 66 + 32 + k];
            int wi = i * 64 + o;
            float e_c = ec[wi], e_s = es[wi];
            float u_c = uc[wi], u_s = us[wi];
            fcu += Scv * e_c + Ssv * e_s + Scu * u_c + Ssu * u_s;
            fsu += Scv * e_s - Ssv * e_c + Scu * u_s - Ssu * u_c;
            if (do_v) {
                float v_c = vc[wi], v_s = vs[wi];
                fcv += Scv * v_c + Ssv * v_s;
                fsv += Scv * v_s - Ssv * v_c;
            }
        }
        wsplit(2.f * fcu, Wub + k);
        wsplit(-2.f * fsu, Wub + 32 + k);
        if (do_v) {
            wsplit(2.f * fcv, Wvb + k);
            wsplit(-2.f * fsv, Wvb + 32 + k);
        }
    } else {
        for (int c = 0; c < 64; ++c) wsplit(wsuw[o * 64 + c], Wub + 64 + c);
        float f0u = 0;
        for (int i = 0; i < 64; ++i)
            f0u += mv[i * 66 + 64] * ew0[i * 64 + o] + mu[i * 66 + 64] * uw0[i * 64 + o];
        biasU[b * 64 + o] = f0u + wsub[o];
        if (do_v) {
            for (int c = 0; c < 64; ++c) wsplit(wsvw[o * 64 + c], Wvb + 64 + c);
            float f0v = 0;
            for (int i = 0; i < 64; ++i) f0v += mv[i * 66 + 64] * vw0[i * 64 + o];
            biasV[b * 64 + o] = f0v + wsvb[o];
        }
    }
}

// ---- fallback buildW (original weight layout) ----
__global__ void k_buildW_slow(const float* __restrict__ momu, const float* __restrict__ momv,
                              const float* __restrict__ ewc, const float* __restrict__ ews, const float* __restrict__ ew0,
                              const float* __restrict__ uwc, const float* __restrict__ uws, const float* __restrict__ uw0,
                              const float* __restrict__ vwc, const float* __restrict__ vws, const float* __restrict__ vw0,
                              const float* __restrict__ wsuw, const float* __restrict__ wsub,
                              const float* __restrict__ wsvw, const float* __restrict__ wsvb,
                              unsigned short* __restrict__ WuBf, unsigned short* __restrict__ WvBf,
                              float* __restrict__ biasU, float* __restrict__ biasV, int do_v) {
    int b = blockIdx.y, j = blockIdx.x, o = threadIdx.x;
    const float* mu = momu + (size_t)b * 64 * 66;
    const float* mv = momv + (size_t)b * 64 * 66;
    unsigned short* Wub = WuBf + ((size_t)b * 64 + o) * 256;
    unsigned short* Wvb = WvBf + ((size_t)b * 64 + o) * 256;
    if (j < 32) {
        int k = j;
        float fcu = 0, fsu = 0, fcv = 0, fsv = 0;
        for (int i = 0; i < 64; ++i) {
            float Scv = mv[i * 66 + k], Ssv = mv[i * 66 + 32 + k];
            float Scu = mu[i * 66 + k], Ssu = mu[i * 66 + 32 + k];
            int wi = (i * 64 + o) * 32 + k;
            float ec = ewc[wi], es = ews[wi];
            float uc = uwc[wi], us = uws[wi];
            fcu += Scv * ec + Ssv * es + Scu * uc + Ssu * us;
            fsu += Scv * es - Ssv * ec + Scu * us - Ssu * uc;
            if (do_v) {
                float vc = vwc[wi], vs = vws[wi];
                fcv += Scv * vc + Ssv * vs;
                fsv += Scv * vs - Ssv * vc;
            }
        }
        wsplit(2.f * fcu, Wub + k);
        wsplit(-2.f * fsu, Wub + 32 + k);
        if (do_v) {
            wsplit(2.f * fcv, Wvb + k);
            wsplit(-2.f * fsv, Wvb + 32 + k);
        }
    } else {
        for (int c = 0; c < 64; ++c) wsplit(wsuw[o * 64 + c], Wub + 64 + c);
        float f0u = 0;
        for (int i = 0; i < 64; ++i)
            f0u += mv[i * 66 + 64] * ew0[i * 64 + o] + mu[i * 66 + 64] * uw0[i * 64 + o];
        biasU[b * 64 + o] = f0u + wsub[o];
        if (do_v) {
            for (int c = 0; c < 64; ++c) wsplit(wsvw[o * 64 + c], Wvb + 64 + c);
            float f0v = 0;
            for (int i = 0; i < 64; ++i) f0v += mv[i * 66 + 64] * vw0[i * 64 + o];
            biasV[b * 64 + o] = f0v + wsvb[o];
        }
    }
}

// ---- fused synthesis u+v (MFMA, no LDS): out = act(Wbf(hi+lo) . FT[x][128] + bias) ----
__global__ __launch_bounds__(256) void k_synth2(const unsigned short* __restrict__ WuBf,
                                                const unsigned short* __restrict__ WvBf,
                                                const float* __restrict__ biasU, const float* __restrict__ biasV,
                                                unsigned short* FTu, unsigned short* FTv,
                                                unsigned short* __restrict__ cbu, unsigned short* __restrict__ cbv,
                                                int NU_, int NV_, int nbu, int act_u, int wch_u) {
    int bx = blockIdx.x, b = blockIdx.y, tid = threadIdx.x;
    const unsigned short* Wb;
    const float* bi;
    unsigned short *FT, *cbp;
    int N, act, wch, blk;
    if (bx < nbu) { Wb = WuBf; bi = biasU; FT = FTu; cbp = cbu; N = NU_; act = act_u; wch = wch_u; blk = bx; }
    else { Wb = WvBf; bi = biasV; FT = FTv; cbp = cbv; N = NV_; act = 1; wch = 1; blk = bx - nbu; }
    int lane = tid & 63, wv = tid >> 6;
    int lm = lane & 15, lg = lane >> 4;
    const unsigned short* Wrow = Wb + ((size_t)b * 64 + 16 * wv + lm) * 256;
    bf16x8 ahi[4], alo[4];
    #pragma unroll
    for (int kt = 0; kt < 4; ++kt) {
        ahi[kt] = *(const bf16x8*)(Wrow + kt * 32 + lg * 8);
        alo[kt] = *(const bf16x8*)(Wrow + 128 + kt * 32 + lg * 8);
    }
    float bias[4];
    #pragma unroll
    for (int j = 0; j < 4; ++j) bias[j] = bi[b * 64 + 16 * wv + lg * 4 + j];
    f32x4 acc[8] = {};
    unsigned short* ftb = FT + (size_t)b * N * 128;
    int x0 = blk * 128;
    #pragma unroll
    for (int xt = 0; xt < 8; ++xt) {
        int x = x0 + xt * 16 + lm;
        const unsigned short* fp = ftb + (size_t)x * 128 + lg * 8;
        #pragma unroll
        for (int kt = 0; kt < 4; ++kt) {
            bf16x8 bf = *(const bf16x8*)(fp + kt * 32);
            acc[xt] = __builtin_amdgcn_mfma_f32_16x16x32_bf16(ahi[kt], bf, acc[xt], 0, 0, 0);
            acc[xt] = __builtin_amdgcn_mfma_f32_16x16x32_bf16(alo[kt], bf, acc[xt], 0, 0, 0);
        }
    }
    __syncthreads();  // all FT reads (all waves) complete before ch-cols overwritten
    int r0 = 16 * wv + lg * 4;
    #pragma unroll
    for (int xt = 0; xt < 8; ++xt) {
        int x = x0 + xt * 16 + lm;
        float v[4];
        #pragma unroll
        for (int j = 0; j < 4; ++j) {
            v[j] = acc[xt][j] + bias[j];
            if (act) v[j] = gelu_f(v[j]);
        }
        unsigned short h[4];
        #pragma unroll
        for (int j = 0; j < 4; ++j) h[j] = f2bf(v[j]);
        if (wch) {
            #pragma unroll
            for (int j = 0; j < 4; ++j) cbp[(size_t)(r0 + j) * N + x] = h[j];
        }
        unsigned int* dst = (unsigned int*)(ftb + (size_t)x * 128 + 64 + r0);
        dst[0] = pk(h[0], h[1]);
        dst[1] = pk(h[2], h[3]);
    }
}

// ---- fc1(gelu)+fc2 fused, MFMA from FT ch-cols ----
__global__ __launch_bounds__(256) void k_fc12(const unsigned short* __restrict__ FT, const float* __restrict__ w1,
                                              const float* __restrict__ b1, const float* __restrict__ w2,
                                              const float* __restrict__ b2, float* __restrict__ out, int N) {
    int b = blockIdx.y, blk = blockIdx.x, tid = threadIdx.x;
    int lane = tid & 63, wv = tid >> 6;
    int lm = lane & 15, lg = lane >> 4;
    int f0 = wv * 32;
    bf16x8 ahi[2][2], alo[2][2];
    #pragma unroll
    for (int ft = 0; ft < 2; ++ft)
        #pragma unroll
        for (int kt = 0; kt < 2; ++kt) {
            const float* wp = w1 + (size_t)(f0 + ft * 16 + lm) * 64 + kt * 32 + lg * 8;
            float tmp[8];
            *(float4*)&tmp[0] = *(const float4*)wp;
            *(float4*)&tmp[4] = *(const float4*)(wp + 4);
            #pragma unroll
            for (int i = 0; i < 8; ++i) {
                unsigned short h = f2bf(tmp[i]);
                ahi[ft][kt][i] = (short)h;
                alo[ft][kt][i] = (short)f2bf(tmp[i] - bf2f(h));
            }
        }
    float b1v[2][4], w2v[2][4];
    #pragma unroll
    for (int ft = 0; ft < 2; ++ft)
        #pragma unroll
        for (int j = 0; j < 4; ++j) {
            int f = f0 + ft * 16 + lg * 4 + j;
            b1v[ft][j] = b1[f];
            w2v[ft][j] = w2[f];
        }
    f32x4 acc[8][2] = {};
    const unsigned short* ftb = FT + (size_t)b * N * 128;
    int x0 = blk * 128;
    #pragma unroll
    for (int xt = 0; xt < 8; ++xt) {
        const unsigned short* fp = ftb + (size_t)(x0 + xt * 16 + lm) * 128 + 64 + lg * 8;
        bf16x8 bf0 = *(const bf16x8*)fp;
        bf16x8 bf1 = *(const bf16x8*)(fp + 32);
        #pragma unroll
        for (int ft = 0; ft < 2; ++ft) {
            acc[xt][ft] = __builtin_amdgcn_mfma_f32_16x16x32_bf16(ahi[ft][0], bf0, acc[xt][ft], 0, 0, 0);
            acc[xt][ft] = __builtin_amdgcn_mfma_f32_16x16x32_bf16(alo[ft][0], bf0, acc[xt][ft], 0, 0, 0);
            acc[xt][ft] = __builtin_amdgcn_mfma_f32_16x16x32_bf16(ahi[ft][1], bf1, acc[xt][ft], 0, 0, 0);
            acc[xt][ft] = __builtin_amdgcn_mfma_f32_16x16x32_bf16(alo[ft][1], bf1, acc[xt][ft], 0, 0, 0);
        }
    }
    __shared__ float red[4][8][16];
    #pragma unroll
    for (int xt = 0; xt < 8; ++xt) {
        float s = 0.f;
        #pragma unroll
        for (int ft = 0; ft < 2; ++ft)
            #pragma unroll
            for (int j = 0; j < 4; ++j) {
                float v = acc[xt][ft][j] + b1v[ft][j];
                s += w2v[ft][j] * gelu_f(v);
            }
        s += __shfl_xor(s, 16, 64);
        s += __shfl_xor(s, 32, 64);
        if (lg == 0) red[wv][xt][lm] = s;
    }
    __syncthreads();
    if (tid < 128) {
        int xt = tid >> 4, lmm = tid & 15;
        float s = b2[0] + red[0][xt][lmm] + red[1][xt][lmm] + red[2][xt][lmm] + red[3][xt][lmm];
        out[(size_t)b * N + x0 + tid] = s;
    }
}

extern "C" void kernel_launch(void* const* d_in, const int* in_sizes, int n_in,
                              void* d_out, int out_size, void* d_ws, size_t ws_size,
                              hipStream_t stream) {
    const float* u_in = (const float*)d_in[0];
    const float* v_in = (const float*)d_in[1];
    const float* nodes_u = (const float*)d_in[3];
    const float* nodes_v = (const float*)d_in[4];
    const float* nwu = (const float*)d_in[5];
    const float* nwv = (const float*)d_in[6];
    const float* modes = (const float*)d_in[7];
    const float* latent = (const float*)d_in[8];
    const float* fc0uw = (const float*)d_in[9];
    const float* fc0ub = (const float*)d_in[10];
    const float* fc0vw = (const float*)d_in[11];
    const float* fc0vb = (const float*)d_in[12];
    const float* ewc = (const float*)d_in[13];
    const float* ews = (const float*)d_in[14];
    const float* ew0 = (const float*)d_in[15];
    const float* uwc = (const float*)d_in[16];
    const float* uws = (const float*)d_in[17];
    const float* uw0 = (const float*)d_in[18];
    const float* vwc = (const float*)d_in[19];
    const float* vws = (const float*)d_in[20];
    const float* vw0 = (const float*)d_in[21];
    const float* wsuw = (const float*)d_in[22];
    const float* wsub = (const float*)d_in[23];
    const float* wsvw = (const float*)d_in[24];
    const float* wsvb = (const float*)d_in[25];
    const float* fc1w = (const float*)d_in[26];
    const float* fc1b = (const float*)d_in[27];
    const float* fc2w = (const float*)d_in[28];
    const float* fc2b = (const float*)d_in[29];
    float* out = (float*)d_out;

    const int B = 4, NU = 65536, NV = 16384;
    const int CH_U = 256, CH_V = 128;

    unsigned short* FT_u = (unsigned short*)d_ws;
    unsigned short* FT_v = FT_u + (size_t)B * NU * 128;
    unsigned short* wbb_u = FT_v + (size_t)B * NV * 128;
    unsigned short* wbb_v = wbb_u + (size_t)B * 65 * NU;
    unsigned short* chbf_u = wbb_v + (size_t)B * 65 * NV;
    unsigned short* chbf_v = chbf_u + (size_t)B * 64 * NU;
    float* part_u = (float*)(chbf_v + (size_t)B * 64 * NV);
    float* part_v = part_u + (size_t)B * CH_U * 64 * 66;
    float* momu = part_v + (size_t)B * CH_V * 64 * 66;
    float* momv = momu + B * 64 * 66;
    unsigned short* WuBf = (unsigned short*)(momv + B * 64 * 66);
    unsigned short* WvBf = WuBf + (size_t)B * 64 * 256;
    float* biasU = (float*)(WvBf + (size_t)B * 64 * 256);
    float* biasV = biasU + B * 64;
    float* wT = biasV + B * 64;
    size_t need_T = (size_t)((char*)(wT + 6 * 393216) - (char*)d_ws);
    int use_T = (ws_size >= need_T) ? 1 : 0;

    k_prep<2><<<dim3(NU / 256, B), 256, 0, stream>>>(nodes_u, modes, latent, nwu, u_in, fc0uw, fc0ub,
                                                     FT_u, wbb_u, chbf_u, NU);
    k_prep<3><<<dim3(NV / 256, B), 256, 0, stream>>>(nodes_v, modes, latent, nwv, v_in, fc0vw, fc0vb,
                                                     FT_v, wbb_v, chbf_v, NV);
    if (use_T)
        k_tw<<<dim3(192, 6), 256, 0, stream>>>(ewc, ews, uwc, uws, vwc, vws, wT);

    for (int l = 0; l < 3; ++l) {
        int do_v = (l < 2) ? 1 : 0;
        k_analysis2<<<dim3(CH_U + CH_V, B), 256, 0, stream>>>(chbf_u, wbb_u, chbf_v, wbb_v,
                                                              part_u, part_v, NU, NV, CH_U, CH_V);
        k_reduce2<<<dim3(17, 2 * B), 256, 0, stream>>>(part_u, part_v, momu, momv, CH_U, CH_V, B);
        if (use_T) {
            k_buildW<<<dim3(33, B), 64, 0, stream>>>(momu, momv,
                wT + 0 * 393216 + l * 131072, wT + 1 * 393216 + l * 131072, ew0 + (size_t)l * 64 * 64,
                wT + 2 * 393216 + l * 131072, wT + 3 * 393216 + l * 131072, uw0 + (size_t)l * 64 * 64,
                wT + 4 * 393216 + l * 131072, wT + 5 * 393216 + l * 131072, vw0 + (size_t)l * 64 * 64,
                wsuw + l * 64 * 64, wsub + l * 64, wsvw + l * 64 * 64, wsvb + l * 64,
                WuBf, WvBf, biasU, biasV, do_v);
        } else {
            k_buildW_slow<<<dim3(33, B), 64, 0, stream>>>(momu, momv,
                ewc + (size_t)l * 64 * 64 * 32, ews + (size_t)l * 64 * 64 * 32, ew0 + (size_t)l * 64 * 64,
                uwc + (size_t)l * 64 * 64 * 32, uws + (size_t)l * 64 * 64 * 32, uw0 + (size_t)l * 64 * 64,
                vwc + (size_t)l * 64 * 64 * 32, vws + (size_t)l * 64 * 64 * 32, vw0 + (size_t)l * 64 * 64,
                wsuw + l * 64 * 64, wsub + l * 64, wsvw + l * 64 * 64, wsvb + l * 64,
                WuBf, WvBf, biasU, biasV, do_v);
        }
        int nbu = NU / 128;
        int nbx = nbu + (do_v ? NV / 128 : 0);
        k_synth2<<<dim3(nbx, B), 256, 0, stream>>>(WuBf, WvBf, biasU, biasV, FT_u, FT_v, chbf_u, chbf_v,
                                                   NU, NV, nbu, do_v, do_v);
    }
    k_fc12<<<dim3(NU / 128, B), 256, 0, stream>>>(FT_u, fc1w, fc1b, fc2w, fc2b, out, NU);
}